// Round 2
// baseline (362.704 us; speedup 1.0000x reference)
//
#include <hip/hip_runtime.h>

#define EPS 1e-5f

namespace {
constexpr int HYPER = 14016;
constexpr int HID   = 192;
constexpr int A1    = 324;   // 18*18
constexpr int A2    = 256;   // 16*16
constexpr int P_TOT = 512;
constexpr int R1OFF = 6144;  // 32*192
constexpr int R2OFF = 7872;  // +192*9

// workspace byte offsets (all 256B-aligned)
constexpr size_t WT_B   = 0;                         // fp32, 28,704,768 B
constexpr size_t X1_B   = 28704768;                  // bf16, 63,700,992 B
constexpr size_t X2_B   = X1_B + 63700992;           // bf16, 50,331,648 B  -> 92,405,760
constexpr size_t X3_B   = X2_B + 50331648;           // fp32, 16,777,216 B  -> 142,737,408
constexpr size_t SUM_B  = X3_B + 16777216;           // fp32, 832*4 B       -> 159,514,624
// sums: [0:192) s1 [192:384) q1 [384:576) s2 [576:768) q2 [768:800) s3 [800:832) q3
}

__device__ __forceinline__ float relu6f(float v) { return fminf(fmaxf(v, 0.f), 6.f); }

__device__ __forceinline__ float bf2f(unsigned int h) {
  return __uint_as_float(h << 16);
}
__device__ __forceinline__ unsigned short f2bf(float f) {
  unsigned int u = __float_as_uint(f);
  return (unsigned short)((u + 0x7FFFu + ((u >> 16) & 1u)) >> 16);
}

// ---------------- K0: transpose s (b, k, f) -> wt[p][k], p = b*64+f ----------------
__global__ __launch_bounds__(256) void k0_transpose(const float* __restrict__ s,
                                                    float* __restrict__ wt) {
  __shared__ float tile[64][65];
  const int blk = blockIdx.x;            // b*219 + kt
  const int b  = blk / 219;
  const int kt = blk - b * 219;
  const int k0 = kt * 64;
  const int t  = threadIdx.x;
  {
    const int f  = t & 63;
    const int kr = t >> 6;
    const float* sp = s + ((size_t)b * HYPER + k0 + kr) * 64 + f;
#pragma unroll
    for (int kk = 0; kk < 16; kk++)
      tile[kr + kk * 4][f] = sp[(size_t)kk * 4 * 64];
  }
  __syncthreads();
  {
    const int kk = t & 63;
    const int fr = t >> 6;
    float* wp = wt + ((size_t)b * 64 + fr) * HYPER + k0 + kk;
#pragma unroll
    for (int ff = 0; ff < 16; ff++)
      wp[(size_t)ff * 4 * HYPER] = tile[kk][fr + ff * 4];
  }
}

// ---------------- K1: pointwise 32->192, writes x1 bf16, accumulates bn1 stats ----------------
__global__ __launch_bounds__(256) void k1_pw1(const float* __restrict__ x,
                                              const float* __restrict__ wt,
                                              unsigned short* __restrict__ x1,
                                              float* __restrict__ sums) {
  __shared__ float pT[32 * 324];   // [c][ij]
  __shared__ float wT[32 * 100];   // [c][o-half] (96 o + pad)
  __shared__ float stat[384];      // ssum[192], ssq[192]
  const int p  = blockIdx.x;
  const int b  = p >> 6;
  const int fi = (p >> 3) & 7;
  const int fj = p & 7;
  const int t  = threadIdx.x;
  const float* wtp = wt + (size_t)p * HYPER;

  for (int i = t; i < 384; i += 256) stat[i] = 0.f;

  // stage patch (reflect-padded gather), c-major
  const int row0 = fi * 16 - 1, col0 = fj * 16 - 1;
  const float* xb = x + (size_t)b * 32 * 128 * 128;
  for (int idx = t; idx < 32 * A1; idx += 256) {
    int c  = idx / A1;
    int ij = idx - c * A1;
    int ii = ij / 18;
    int jj = ij - ii * 18;
    int r  = row0 + ii; r  = (r  < 0) ? 1 : (r  > 127) ? 126 : r;
    int cl = col0 + jj; cl = (cl < 0) ? 1 : (cl > 127) ? 126 : cl;
    pT[c * 324 + ij] = xb[((size_t)c * 128 + r) * 128 + cl];
  }

  for (int half = 0; half < 2; half++) {
    // stage 96 output channels of w1: wt idx = o*32 + c
    for (int idx = t; idx < 96 * 32; idx += 256) {
      int o = idx >> 5, c = idx & 31;
      wT[c * 100 + o] = wtp[half * 3072 + idx];
    }
    __syncthreads();
    for (int ti = t; ti < 81 * 12; ti += 256) {
      int tij = ti % 81;
      int to  = ti / 81;
      int ij0 = tij * 4, o0 = to * 8;
      float acc[4][8];
#pragma unroll
      for (int q = 0; q < 4; q++)
#pragma unroll
        for (int oo = 0; oo < 8; oo++) acc[q][oo] = 0.f;
#pragma unroll 4
      for (int c = 0; c < 32; c++) {
        float4 pv = *(const float4*)&pT[c * 324 + ij0];
        float4 wa = *(const float4*)&wT[c * 100 + o0];
        float4 wb = *(const float4*)&wT[c * 100 + o0 + 4];
        float pq[4] = {pv.x, pv.y, pv.z, pv.w};
        float wo[8] = {wa.x, wa.y, wa.z, wa.w, wb.x, wb.y, wb.z, wb.w};
#pragma unroll
        for (int q = 0; q < 4; q++)
#pragma unroll
          for (int oo = 0; oo < 8; oo++)
            acc[q][oo] = fmaf(pq[q], wo[oo], acc[q][oo]);
      }
      // round to bf16, store vectorized, accumulate stats of rounded values
      unsigned short* dst = x1 + ((size_t)p * A1 + ij0) * HID + half * 96 + o0;
      float so[8], qo[8];
#pragma unroll
      for (int oo = 0; oo < 8; oo++) { so[oo] = 0.f; qo[oo] = 0.f; }
#pragma unroll
      for (int q = 0; q < 4; q++) {
        unsigned int h[8];
#pragma unroll
        for (int oo = 0; oo < 8; oo++) {
          h[oo] = f2bf(acc[q][oo]);
          float r = bf2f(h[oo]);
          so[oo] += r;
          qo[oo] = fmaf(r, r, qo[oo]);
        }
        uint4 pk;
        pk.x = h[0] | (h[1] << 16);
        pk.y = h[2] | (h[3] << 16);
        pk.z = h[4] | (h[5] << 16);
        pk.w = h[6] | (h[7] << 16);
        *(uint4*)(dst + (size_t)q * HID) = pk;
      }
#pragma unroll
      for (int oo = 0; oo < 8; oo++) {
        atomicAdd(&stat[half * 96 + o0 + oo], so[oo]);
        atomicAdd(&stat[192 + half * 96 + o0 + oo], qo[oo]);
      }
    }
    __syncthreads();
  }
  for (int i = t; i < 384; i += 256) atomicAdd(&sums[i], stat[i]);
}

// ---------------- K2: bn1+relu6, depthwise 3x3, writes x2 bf16, bn2 stats ----------------
__global__ __launch_bounds__(256) void k2_dw(const unsigned short* __restrict__ x1,
                                             const float* __restrict__ wt,
                                             const float* __restrict__ sums,
                                             const float* __restrict__ g1,
                                             const float* __restrict__ b1,
                                             unsigned short* __restrict__ x2,
                                             float* __restrict__ sums2) {
  __shared__ float xc[A1 * 33];     // [ij][32ch + pad]
  __shared__ float w2L[HID * 9];
  __shared__ float sc[HID], sh[HID];
  __shared__ float st2[384];
  const int p = blockIdx.x;
  const int t = threadIdx.x;
  const float inv = 1.f / 165888.f;    // 512*324
  for (int c = t; c < HID; c += 256) {
    float m   = sums[c] * inv;
    float var = sums[192 + c] * inv - m * m;
    float scl = g1[c] * rsqrtf(var + EPS);
    sc[c] = scl;
    sh[c] = b1[c] - m * scl;
  }
  for (int i = t; i < 384; i += 256) st2[i] = 0.f;
  const float* wtp = wt + (size_t)p * HYPER + R1OFF;
  for (int i = t; i < HID * 9; i += 256) w2L[i] = wtp[i];
  __syncthreads();
  const int cc = t & 31;
  const int jb = t >> 5;   // 0..7
  const unsigned short* x1p = x1 + (size_t)p * A1 * HID;
  unsigned short* x2p = x2 + (size_t)p * A2 * HID;
  for (int cb = 0; cb < HID; cb += 32) {
    // stage 32 channels, bn1+relu6 applied
    for (int i = t; i < A1 * 8; i += 256) {
      int quad = i & 7;
      int ij   = i >> 3;
      int c    = cb + quad * 4;
      uint2 uv = *(const uint2*)&x1p[(size_t)ij * HID + c];
      float v0 = bf2f(uv.x & 0xFFFFu);
      float v1 = bf2f(uv.x >> 16);
      float v2 = bf2f(uv.y & 0xFFFFu);
      float v3 = bf2f(uv.y >> 16);
      v0 = relu6f(fmaf(v0, sc[c],     sh[c]));
      v1 = relu6f(fmaf(v1, sc[c + 1], sh[c + 1]));
      v2 = relu6f(fmaf(v2, sc[c + 2], sh[c + 2]));
      v3 = relu6f(fmaf(v3, sc[c + 3], sh[c + 3]));
      float* d = &xc[ij * 33 + quad * 4];
      d[0] = v0; d[1] = v1; d[2] = v2; d[3] = v3;
    }
    __syncthreads();
    float wr[9];
#pragma unroll
    for (int uv = 0; uv < 9; uv++) wr[uv] = w2L[(cb + cc) * 9 + uv];
    float ls = 0.f, lq = 0.f;
#pragma unroll
    for (int it = 0; it < 2; it++) {
      const int j = jb + it * 8;
      float accs[20];
#pragma unroll
      for (int i = 0; i < 20; i++) accs[i] = 0.f;
#pragma unroll
      for (int r = 0; r < 18; r++) {
        const float* base = &xc[(r * 18 + j) * 33 + cc];
        float v0 = base[0], v1 = base[33], v2 = base[66];
#pragma unroll
        for (int u = 0; u < 3; u++) {
          float a = accs[r - u + 2];
          a = fmaf(v0, wr[u * 3 + 0], a);
          a = fmaf(v1, wr[u * 3 + 1], a);
          a = fmaf(v2, wr[u * 3 + 2], a);
          accs[r - u + 2] = a;
        }
      }
#pragma unroll
      for (int i = 0; i < 16; i++) {
        unsigned int h = f2bf(accs[i + 2]);
        float rv = bf2f(h);
        ls += rv;
        lq = fmaf(rv, rv, lq);
        x2p[(size_t)(i * 16 + j) * HID + cb + cc] = (unsigned short)h;
      }
    }
    atomicAdd(&st2[cb + cc], ls);
    atomicAdd(&st2[192 + cb + cc], lq);
    __syncthreads();
  }
  for (int i = t; i < 384; i += 256) atomicAdd(&sums2[i], st2[i]);
}

// ---------------- K3: bn2+relu6, pointwise 192->32, writes x3 fp32, bn3 stats ----------------
__global__ __launch_bounds__(256) void k3_pw2(const unsigned short* __restrict__ x2,
                                              const float* __restrict__ wt,
                                              const float* __restrict__ sums2,
                                              const float* __restrict__ g2,
                                              const float* __restrict__ b2,
                                              float* __restrict__ x3,
                                              float* __restrict__ sums3) {
  __shared__ float xT[32 * 260];    // [c-chunk][ij + pad]
  __shared__ float w3L[HID * 36];   // [c][o + pad]
  __shared__ float sc[HID], sh[HID];
  __shared__ float st3[64];
  const int p = blockIdx.x;
  const int t = threadIdx.x;
  const float inv = 1.f / 131072.f;   // 512*256
  for (int c = t; c < HID; c += 256) {
    float m   = sums2[c] * inv;
    float var = sums2[192 + c] * inv - m * m;
    float scl = g2[c] * rsqrtf(var + EPS);
    sc[c] = scl;
    sh[c] = b2[c] - m * scl;
  }
  if (t < 64) st3[t] = 0.f;
  const float* wtp = wt + (size_t)p * HYPER + R2OFF;
  for (int i = t; i < 32 * HID; i += 256) {
    int o = i / HID;
    int c = i - o * HID;
    w3L[c * 36 + o] = wtp[i];
  }
  const int ij0 = (t & 63) * 4;
  const int o0  = (t >> 6) * 8;
  const int quad = t & 7;
  const int ijs  = t >> 3;
  float acc[4][8];
#pragma unroll
  for (int q = 0; q < 4; q++)
#pragma unroll
    for (int oo = 0; oo < 8; oo++) acc[q][oo] = 0.f;
  const unsigned short* x2p = x2 + (size_t)p * A2 * HID;
  __syncthreads();
  for (int cb = 0; cb < HID; cb += 32) {
#pragma unroll
    for (int it = 0; it < 8; it++) {
      int ij = ijs + it * 32;
      int c  = cb + quad * 4;
      uint2 uv = *(const uint2*)&x2p[(size_t)ij * HID + c];
      float v0 = bf2f(uv.x & 0xFFFFu);
      float v1 = bf2f(uv.x >> 16);
      float v2 = bf2f(uv.y & 0xFFFFu);
      float v3 = bf2f(uv.y >> 16);
      v0 = relu6f(fmaf(v0, sc[c],     sh[c]));
      v1 = relu6f(fmaf(v1, sc[c + 1], sh[c + 1]));
      v2 = relu6f(fmaf(v2, sc[c + 2], sh[c + 2]));
      v3 = relu6f(fmaf(v3, sc[c + 3], sh[c + 3]));
      float* d = &xT[quad * 4 * 260 + ij];
      d[0] = v0; d[260] = v1; d[520] = v2; d[780] = v3;
    }
    __syncthreads();
#pragma unroll 4
    for (int k = 0; k < 32; k++) {
      float4 xv = *(const float4*)&xT[k * 260 + ij0];
      float4 wa = *(const float4*)&w3L[(cb + k) * 36 + o0];
      float4 wb = *(const float4*)&w3L[(cb + k) * 36 + o0 + 4];
      float xq[4] = {xv.x, xv.y, xv.z, xv.w};
      float wo[8] = {wa.x, wa.y, wa.z, wa.w, wb.x, wb.y, wb.z, wb.w};
#pragma unroll
      for (int q = 0; q < 4; q++)
#pragma unroll
        for (int oo = 0; oo < 8; oo++)
          acc[q][oo] = fmaf(xq[q], wo[oo], acc[q][oo]);
    }
    __syncthreads();
  }
  // x3 layout [p][o][ij]; accumulate bn3 stats
  float* x3p = x3 + (size_t)p * 32 * A2;
#pragma unroll
  for (int oo = 0; oo < 8; oo++) {
    float4 v = make_float4(acc[0][oo], acc[1][oo], acc[2][oo], acc[3][oo]);
    *(float4*)&x3p[(size_t)(o0 + oo) * A2 + ij0] = v;
    float so = v.x + v.y + v.z + v.w;
    float qo = fmaf(v.x, v.x, fmaf(v.y, v.y, fmaf(v.z, v.z, v.w * v.w)));
    atomicAdd(&st3[o0 + oo], so);
    atomicAdd(&st3[32 + o0 + oo], qo);
  }
  __syncthreads();
  if (t < 64) atomicAdd(&sums3[t], st3[t]);
}

// ---------------- K4: bn3 + residual + layout transform ----------------
__global__ __launch_bounds__(256) void k4_out(const float* __restrict__ x,
                                              const float* __restrict__ x3,
                                              const float* __restrict__ sums3,
                                              const float* __restrict__ g3,
                                              const float* __restrict__ b3,
                                              float* __restrict__ out) {
  const int idx4 = blockIdx.x * 256 + threadIdx.x;   // 1,048,576 float4 total
  const int w4 = idx4 & 31;
  int tmp = idx4 >> 5;
  const int h = tmp & 127; tmp >>= 7;
  const int o = tmp & 31;
  const int b = tmp >> 5;
  const int fi = h >> 4, i = h & 15;
  const int fj = w4 >> 2;
  const int j0 = (w4 & 3) * 4;
  const int p   = b * 64 + fi * 8 + fj;
  const int ij0 = i * 16 + j0;
  const float inv = 1.f / 131072.f;
  float m   = sums3[o] * inv;
  float var = sums3[32 + o] * inv - m * m;
  float sv  = g3[o] * rsqrtf(var + EPS);
  float shv = b3[o] - m * sv;
  float4 xv = *(const float4*)&x[(size_t)idx4 * 4];
  float4 v  = *(const float4*)&x3[((size_t)p * 32 + o) * A2 + ij0];
  float4 r;
  r.x = fmaf(v.x, sv, shv) + xv.x;
  r.y = fmaf(v.y, sv, shv) + xv.y;
  r.z = fmaf(v.z, sv, shv) + xv.z;
  r.w = fmaf(v.w, sv, shv) + xv.w;
  *(float4*)&out[(size_t)idx4 * 4] = r;
}

extern "C" void kernel_launch(void* const* d_in, const int* in_sizes, int n_in,
                              void* d_out, int out_size, void* d_ws, size_t ws_size,
                              hipStream_t stream) {
  const float* x  = (const float*)d_in[0];
  const float* s  = (const float*)d_in[1];
  const float* g1 = (const float*)d_in[2];
  const float* b1 = (const float*)d_in[3];
  const float* g2 = (const float*)d_in[4];
  const float* b2 = (const float*)d_in[5];
  const float* g3 = (const float*)d_in[6];
  const float* b3 = (const float*)d_in[7];
  char* base = (char*)d_ws;
  float*          wt   = (float*)(base + WT_B);
  unsigned short* x1   = (unsigned short*)(base + X1_B);
  unsigned short* x2   = (unsigned short*)(base + X2_B);
  float*          x3   = (float*)(base + X3_B);
  float*          sums = (float*)(base + SUM_B);
  float* out = (float*)d_out;

  hipMemsetAsync(sums, 0, 832 * sizeof(float), stream);
  k0_transpose<<<8 * 219, 256, 0, stream>>>(s, wt);
  k1_pw1<<<P_TOT, 256, 0, stream>>>(x, wt, x1, sums);
  k2_dw<<<P_TOT, 256, 0, stream>>>(x1, wt, sums, g1, b1, x2, sums + 384);
  k3_pw2<<<P_TOT, 256, 0, stream>>>(x2, wt, sums + 384, g2, b2, x3, sums + 768);
  k4_out<<<4096, 256, 0, stream>>>(x, x3, sums + 768, g3, b3, out);
}

// Round 3
// 245.819 us; speedup vs baseline: 1.4755x; 1.4755x over previous
//
#include <hip/hip_runtime.h>

#define EPS 1e-5f

namespace {
constexpr int HYPER = 14016;
constexpr int HID   = 192;
constexpr int A1    = 324;   // 18*18
constexpr int A2    = 256;   // 16*16
constexpr int P_TOT = 512;
constexpr int W1SZ  = 6144;  // 32*192
constexpr int WT2SZ = 7872;  // w2 (1728) + w3 (6144)
constexpr int R3OFF = 1728;  // w3 offset inside wt2

// workspace byte offsets
constexpr size_t WB1_B = 0;                       // bf16 w1 [p][o][c], 6,291,456 B
constexpr size_t WT2_B = 6291456;                 // fp32 w2+w3 [p][7872], 16,121,856 B
constexpr size_t X1_B  = WT2_B + 16121856;        // bf16 x1 [p][192][324], 63,700,992 B
constexpr size_t X2_B  = X1_B + 63700992;         // bf16 x2 [p][256][192], 50,331,648 B
constexpr size_t X3_B  = X2_B + 50331648;         // fp32 x3 [p][32][256], 16,777,216 B
constexpr size_t SUM_B = X3_B + 16777216;         // fp32 832 floats
// sums: [0:192) s1 [192:384) q1 [384:576) s2 [576:768) q2 [768:800) s3 [800:832) q3
}

typedef __attribute__((ext_vector_type(8))) short bf16x8;
typedef __attribute__((ext_vector_type(4))) float f32x4;

__device__ __forceinline__ float relu6f(float v) { return fminf(fmaxf(v, 0.f), 6.f); }

__device__ __forceinline__ float bf2f(unsigned int h) {
  return __uint_as_float(h << 16);
}
__device__ __forceinline__ unsigned short f2bf(float f) {
  unsigned int u = __float_as_uint(f);
  return (unsigned short)((u + 0x7FFFu + ((u >> 16) & 1u)) >> 16);
}

// ---------------- K0: transpose s; w1 -> bf16 wb1[p][o*32+c], rest -> fp32 wt2 ----------------
__global__ __launch_bounds__(256) void k0_transpose(const float* __restrict__ s,
                                                    unsigned short* __restrict__ wb1,
                                                    float* __restrict__ wt2) {
  __shared__ float tile[64][65];
  const int blk = blockIdx.x;            // b*219 + kt
  const int b  = blk / 219;
  const int kt = blk - b * 219;
  const int k0 = kt * 64;
  const int t  = threadIdx.x;
  {
    const int f  = t & 63;
    const int kr = t >> 6;
    const float* sp = s + ((size_t)b * HYPER + k0 + kr) * 64 + f;
#pragma unroll
    for (int kk = 0; kk < 16; kk++)
      tile[kr + kk * 4][f] = sp[(size_t)kk * 4 * 64];
  }
  __syncthreads();
  {
    const int kk = t & 63;
    const int fr = t >> 6;
    if (kt < 96) {   // w1 region (k < 6144), emit bf16
      unsigned short* wp = wb1 + ((size_t)b * 64 + fr) * W1SZ + k0 + kk;
#pragma unroll
      for (int ff = 0; ff < 16; ff++)
        wp[(size_t)ff * 4 * W1SZ] = f2bf(tile[kk][fr + ff * 4]);
    } else {
      float* wp = wt2 + ((size_t)b * 64 + fr) * WT2SZ + (k0 - W1SZ) + kk;
#pragma unroll
      for (int ff = 0; ff < 16; ff++)
        wp[(size_t)ff * 4 * WT2SZ] = tile[kk][fr + ff * 4];
    }
  }
}

// ---------------- K1: MFMA pointwise 32->192, x1 bf16 [p][o][324], bn1 stats ----------------
// LDS operands in fragment-contiguous order: slot = tile*512 + lane*8 + j
__global__ __launch_bounds__(256) void k1_pw1(const float* __restrict__ x,
                                              const unsigned short* __restrict__ wb1,
                                              unsigned short* __restrict__ x1,
                                              float* __restrict__ sums) {
  __shared__ __align__(16) unsigned short pL[21 * 512];   // B frags: 21 ij-tiles
  __shared__ __align__(16) unsigned short wA[12 * 512];   // A frags: 12 o-tiles
  __shared__ float stat[384];
  const int p  = blockIdx.x;
  const int b  = p >> 6;
  const int fi = (p >> 3) & 7;
  const int fj = p & 7;
  const int t  = threadIdx.x;

  for (int i = t; i < 384; i += 256) stat[i] = 0.f;

  // stage w1 frags: value A[o][c], slot ((o>>4)*4 + (c>>3))*128 + (o&15)*8 + (c&7)
  const unsigned short* wbp = wb1 + (size_t)p * W1SZ;
  for (int idx = t; idx < 1536; idx += 256) {     // ushort4 granules
    int o  = idx >> 3;
    int c4 = idx & 7;
    ushort4 v = *(const ushort4*)&wbp[idx * 4];
    int slot = ((o >> 4) * 4 + (c4 >> 1)) * 128 + (o & 15) * 8 + (c4 & 1) * 4;
    *(ushort4*)&wA[slot] = v;
  }
  // stage patch frags: value B[c][ij] = patch[ij][c] (reflect-pad gather)
  const int row0 = fi * 16 - 1, col0 = fj * 16 - 1;
  const float* xb = x + (size_t)b * 32 * 128 * 128;
  for (int idx = t; idx < 32 * A1; idx += 256) {
    int c  = idx / A1;
    int ij = idx - c * A1;
    int ii = ij / 18;
    int jj = ij - ii * 18;
    int r  = row0 + ii; r  = (r  < 0) ? 1 : (r  > 127) ? 126 : r;
    int cl = col0 + jj; cl = (cl < 0) ? 1 : (cl > 127) ? 126 : cl;
    int slot = ((ij >> 4) * 4 + (c >> 3)) * 128 + (ij & 15) * 8 + (c & 7);
    pL[slot] = f2bf(xb[((size_t)c * 128 + r) * 128 + cl]);
  }
  __syncthreads();

  const int lane = t & 63;
  const int wv   = t >> 6;
  const int m16  = lane & 15;
  const int quad = lane >> 4;
  unsigned short* x1p = x1 + (size_t)p * HID * A1;

  for (int oi = 0; oi < 3; oi++) {
    const int ot = wv + oi * 4;                       // 0..11 across 4 waves
    bf16x8 a = *(const bf16x8*)&wA[ot * 512 + lane * 8];
    float sacc[4] = {0.f, 0.f, 0.f, 0.f};
    float qacc[4] = {0.f, 0.f, 0.f, 0.f};
    for (int jt = 0; jt < 21; jt++) {
      bf16x8 bb = *(const bf16x8*)&pL[jt * 512 + lane * 8];
      f32x4 d = __builtin_amdgcn_mfma_f32_16x16x32_bf16(a, bb, (f32x4){0.f, 0.f, 0.f, 0.f}, 0, 0, 0);
      const int ij = jt * 16 + m16;                   // D col = lane&15
      if (ij < A1) {
        unsigned short* dst = x1p + (size_t)(ot * 16 + quad * 4) * A1 + ij;
#pragma unroll
        for (int r = 0; r < 4; r++) {                 // D row = quad*4 + r
          float v = d[r];
          sacc[r] += v;
          qacc[r] = fmaf(v, v, qacc[r]);
          dst[(size_t)r * A1] = f2bf(v);
        }
      }
    }
#pragma unroll
    for (int r = 0; r < 4; r++) {
      float sv = sacc[r], qv = qacc[r];
#pragma unroll
      for (int msk = 1; msk < 16; msk <<= 1) {
        sv += __shfl_xor(sv, msk, 64);
        qv += __shfl_xor(qv, msk, 64);
      }
      if (m16 == 0) {
        int o = ot * 16 + quad * 4 + r;
        atomicAdd(&stat[o], sv);
        atomicAdd(&stat[192 + o], qv);
      }
    }
  }
  __syncthreads();
  for (int i = t; i < 384; i += 256) atomicAdd(&sums[i], stat[i]);
}

// ---------------- K2: bn1+relu6, depthwise 3x3, writes x2 bf16 [p][ij][c], bn2 stats ----------------
__global__ __launch_bounds__(256) void k2_dw(const unsigned short* __restrict__ x1,
                                             const float* __restrict__ wt2,
                                             const float* __restrict__ sums,
                                             const float* __restrict__ g1,
                                             const float* __restrict__ b1,
                                             unsigned short* __restrict__ x2,
                                             float* __restrict__ sums2) {
  __shared__ float xc[A1 * 33];     // [ij][32ch + pad]
  __shared__ float w2L[HID * 9];
  __shared__ float sc[HID], sh[HID];
  __shared__ float st2[384];
  const int p = blockIdx.x;
  const int t = threadIdx.x;
  const float inv = 1.f / 165888.f;    // 512*324
  for (int c = t; c < HID; c += 256) {
    float m   = sums[c] * inv;
    float var = sums[192 + c] * inv - m * m;
    float scl = g1[c] * rsqrtf(var + EPS);
    sc[c] = scl;
    sh[c] = b1[c] - m * scl;
  }
  for (int i = t; i < 384; i += 256) st2[i] = 0.f;
  const float* wtp = wt2 + (size_t)p * WT2SZ;       // w2 at offset 0
  for (int i = t; i < HID * 9; i += 256) w2L[i] = wtp[i];
  __syncthreads();
  const int cc = t & 31;
  const int jb = t >> 5;   // 0..7
  const unsigned short* x1p = x1 + (size_t)p * HID * A1;
  unsigned short* x2p = x2 + (size_t)p * A2 * HID;
  for (int cb = 0; cb < HID; cb += 32) {
    // stage 32 channels from o-major x1, bn1+relu6 applied
    for (int idx = t; idx < 32 * 81; idx += 256) {
      int g = idx % 81;                 // ushort4 group along ij
      int c = idx / 81;                 // 0..31
      int ij = g * 4;
      ushort4 uv = *(const ushort4*)&x1p[(size_t)(cb + c) * A1 + ij];
      float scl = sc[cb + c], shv = sh[cb + c];
      xc[(ij + 0) * 33 + c] = relu6f(fmaf(bf2f(uv.x), scl, shv));
      xc[(ij + 1) * 33 + c] = relu6f(fmaf(bf2f(uv.y), scl, shv));
      xc[(ij + 2) * 33 + c] = relu6f(fmaf(bf2f(uv.z), scl, shv));
      xc[(ij + 3) * 33 + c] = relu6f(fmaf(bf2f(uv.w), scl, shv));
    }
    __syncthreads();
    float wr[9];
#pragma unroll
    for (int uv = 0; uv < 9; uv++) wr[uv] = w2L[(cb + cc) * 9 + uv];
    float ls = 0.f, lq = 0.f;
#pragma unroll
    for (int it = 0; it < 2; it++) {
      const int j = jb + it * 8;
      float accs[20];
#pragma unroll
      for (int i = 0; i < 20; i++) accs[i] = 0.f;
#pragma unroll
      for (int r = 0; r < 18; r++) {
        const float* base = &xc[(r * 18 + j) * 33 + cc];
        float v0 = base[0], v1 = base[33], v2 = base[66];
#pragma unroll
        for (int u = 0; u < 3; u++) {
          float a = accs[r - u + 2];
          a = fmaf(v0, wr[u * 3 + 0], a);
          a = fmaf(v1, wr[u * 3 + 1], a);
          a = fmaf(v2, wr[u * 3 + 2], a);
          accs[r - u + 2] = a;
        }
      }
#pragma unroll
      for (int i = 0; i < 16; i++) {
        unsigned int h = f2bf(accs[i + 2]);
        float rv = bf2f(h);
        ls += rv;
        lq = fmaf(rv, rv, lq);
        x2p[(size_t)(i * 16 + j) * HID + cb + cc] = (unsigned short)h;
      }
    }
    atomicAdd(&st2[cb + cc], ls);
    atomicAdd(&st2[192 + cb + cc], lq);
    __syncthreads();
  }
  for (int i = t; i < 384; i += 256) atomicAdd(&sums2[i], st2[i]);
}

// ---------------- K3: bn2+relu6, pointwise 192->32, x3 fp32 [p][o][ij], bn3 stats ----------------
__global__ __launch_bounds__(256) void k3_pw2(const unsigned short* __restrict__ x2,
                                              const float* __restrict__ wt2,
                                              const float* __restrict__ sums2,
                                              const float* __restrict__ g2,
                                              const float* __restrict__ b2,
                                              float* __restrict__ x3,
                                              float* __restrict__ sums3) {
  __shared__ float xT[32 * 260];    // [c-chunk][ij + pad]
  __shared__ float w3L[HID * 36];   // [c][o + pad]
  __shared__ float sc[HID], sh[HID];
  __shared__ float st3[64];
  const int p = blockIdx.x;
  const int t = threadIdx.x;
  const float inv = 1.f / 131072.f;   // 512*256
  for (int c = t; c < HID; c += 256) {
    float m   = sums2[c] * inv;
    float var = sums2[192 + c] * inv - m * m;
    float scl = g2[c] * rsqrtf(var + EPS);
    sc[c] = scl;
    sh[c] = b2[c] - m * scl;
  }
  if (t < 64) st3[t] = 0.f;
  const float* wtp = wt2 + (size_t)p * WT2SZ + R3OFF;
  for (int i = t; i < 32 * HID; i += 256) {
    int o = i / HID;
    int c = i - o * HID;
    w3L[c * 36 + o] = wtp[i];
  }
  const int ij0 = (t & 63) * 4;
  const int o0  = (t >> 6) * 8;
  const int quad = t & 7;
  const int ijs  = t >> 3;
  float acc[4][8];
#pragma unroll
  for (int q = 0; q < 4; q++)
#pragma unroll
    for (int oo = 0; oo < 8; oo++) acc[q][oo] = 0.f;
  const unsigned short* x2p = x2 + (size_t)p * A2 * HID;
  __syncthreads();
  for (int cb = 0; cb < HID; cb += 32) {
#pragma unroll
    for (int it = 0; it < 8; it++) {
      int ij = ijs + it * 32;
      int c  = cb + quad * 4;
      ushort4 uv = *(const ushort4*)&x2p[(size_t)ij * HID + c];
      float v0 = relu6f(fmaf(bf2f(uv.x), sc[c],     sh[c]));
      float v1 = relu6f(fmaf(bf2f(uv.y), sc[c + 1], sh[c + 1]));
      float v2 = relu6f(fmaf(bf2f(uv.z), sc[c + 2], sh[c + 2]));
      float v3 = relu6f(fmaf(bf2f(uv.w), sc[c + 3], sh[c + 3]));
      float* d = &xT[quad * 4 * 260 + ij];
      d[0] = v0; d[260] = v1; d[520] = v2; d[780] = v3;
    }
    __syncthreads();
#pragma unroll 4
    for (int k = 0; k < 32; k++) {
      float4 xv = *(const float4*)&xT[k * 260 + ij0];
      float4 wa = *(const float4*)&w3L[(cb + k) * 36 + o0];
      float4 wb = *(const float4*)&w3L[(cb + k) * 36 + o0 + 4];
      float xq[4] = {xv.x, xv.y, xv.z, xv.w};
      float wo[8] = {wa.x, wa.y, wa.z, wa.w, wb.x, wb.y, wb.z, wb.w};
#pragma unroll
      for (int q = 0; q < 4; q++)
#pragma unroll
        for (int oo = 0; oo < 8; oo++)
          acc[q][oo] = fmaf(xq[q], wo[oo], acc[q][oo]);
    }
    __syncthreads();
  }
  float* x3p = x3 + (size_t)p * 32 * A2;
#pragma unroll
  for (int oo = 0; oo < 8; oo++) {
    float4 v = make_float4(acc[0][oo], acc[1][oo], acc[2][oo], acc[3][oo]);
    *(float4*)&x3p[(size_t)(o0 + oo) * A2 + ij0] = v;
    float so = v.x + v.y + v.z + v.w;
    float qo = fmaf(v.x, v.x, fmaf(v.y, v.y, fmaf(v.z, v.z, v.w * v.w)));
    atomicAdd(&st3[o0 + oo], so);
    atomicAdd(&st3[32 + o0 + oo], qo);
  }
  __syncthreads();
  if (t < 64) atomicAdd(&sums3[t], st3[t]);
}

// ---------------- K4: bn3 + residual + layout transform ----------------
__global__ __launch_bounds__(256) void k4_out(const float* __restrict__ x,
                                              const float* __restrict__ x3,
                                              const float* __restrict__ sums3,
                                              const float* __restrict__ g3,
                                              const float* __restrict__ b3,
                                              float* __restrict__ out) {
  const int idx4 = blockIdx.x * 256 + threadIdx.x;   // 1,048,576 float4 total
  const int w4 = idx4 & 31;
  int tmp = idx4 >> 5;
  const int h = tmp & 127; tmp >>= 7;
  const int o = tmp & 31;
  const int b = tmp >> 5;
  const int fi = h >> 4, i = h & 15;
  const int fj = w4 >> 2;
  const int j0 = (w4 & 3) * 4;
  const int p   = b * 64 + fi * 8 + fj;
  const int ij0 = i * 16 + j0;
  const float inv = 1.f / 131072.f;
  float m   = sums3[o] * inv;
  float var = sums3[32 + o] * inv - m * m;
  float sv  = g3[o] * rsqrtf(var + EPS);
  float shv = b3[o] - m * sv;
  float4 xv = *(const float4*)&x[(size_t)idx4 * 4];
  float4 v  = *(const float4*)&x3[((size_t)p * 32 + o) * A2 + ij0];
  float4 r;
  r.x = fmaf(v.x, sv, shv) + xv.x;
  r.y = fmaf(v.y, sv, shv) + xv.y;
  r.z = fmaf(v.z, sv, shv) + xv.z;
  r.w = fmaf(v.w, sv, shv) + xv.w;
  *(float4*)&out[(size_t)idx4 * 4] = r;
}

extern "C" void kernel_launch(void* const* d_in, const int* in_sizes, int n_in,
                              void* d_out, int out_size, void* d_ws, size_t ws_size,
                              hipStream_t stream) {
  const float* x  = (const float*)d_in[0];
  const float* s  = (const float*)d_in[1];
  const float* g1 = (const float*)d_in[2];
  const float* b1 = (const float*)d_in[3];
  const float* g2 = (const float*)d_in[4];
  const float* b2 = (const float*)d_in[5];
  const float* g3 = (const float*)d_in[6];
  const float* b3 = (const float*)d_in[7];
  char* base = (char*)d_ws;
  unsigned short* wb1  = (unsigned short*)(base + WB1_B);
  float*          wt2  = (float*)(base + WT2_B);
  unsigned short* x1   = (unsigned short*)(base + X1_B);
  unsigned short* x2   = (unsigned short*)(base + X2_B);
  float*          x3   = (float*)(base + X3_B);
  float*          sums = (float*)(base + SUM_B);
  float* out = (float*)d_out;

  hipMemsetAsync(sums, 0, 832 * sizeof(float), stream);
  k0_transpose<<<8 * 219, 256, 0, stream>>>(s, wb1, wt2);
  k1_pw1<<<P_TOT, 256, 0, stream>>>(x, wb1, x1, sums);
  k2_dw<<<P_TOT, 256, 0, stream>>>(x1, wt2, sums, g1, b1, x2, sums + 384);
  k3_pw2<<<P_TOT, 256, 0, stream>>>(x2, wt2, sums + 384, g2, b2, x3, sums + 768);
  k4_out<<<4096, 256, 0, stream>>>(x, x3, sums + 768, g3, b3, out);
}

// Round 5
// 235.735 us; speedup vs baseline: 1.5386x; 1.0428x over previous
//
#include <hip/hip_runtime.h>

#define EPS 1e-5f

namespace {
constexpr int HYPER = 14016;
constexpr int HID   = 192;
constexpr int A1    = 324;   // 18*18
constexpr int A2    = 256;   // 16*16
constexpr int P_TOT = 512;
constexpr int W1SZ  = 6144;  // 32*192
constexpr int WT2SZ = 7872;  // w2 (1728) + w3 (6144)
constexpr int R3OFF = 1728;  // w3 offset inside wt2

// workspace byte offsets
constexpr size_t WB1_B = 0;                       // bf16 w1 [p][o][c], 6,291,456 B
constexpr size_t WT2_B = 6291456;                 // fp32 w2+w3 [p][7872], 16,121,856 B
constexpr size_t X1_B  = WT2_B + 16121856;        // bf16 x1 [p][192][324], 63,700,992 B
constexpr size_t X2_B  = X1_B + 63700992;         // bf16 x2 [p][256][192], 50,331,648 B
constexpr size_t X3_B  = X2_B + 50331648;         // fp32 x3 [p][32][256], 16,777,216 B
constexpr size_t SUM_B = X3_B + 16777216;         // fp32 832 floats
// sums: [0:192) s1 [192:384) q1 [384:576) s2 [576:768) q2 [768:800) s3 [800:832) q3
}

typedef __attribute__((ext_vector_type(8))) short bf16x8;
typedef __attribute__((ext_vector_type(4))) float f32x4;

__device__ __forceinline__ float relu6f(float v) { return fminf(fmaxf(v, 0.f), 6.f); }

__device__ __forceinline__ float bf2f(unsigned int h) {
  return __uint_as_float(h << 16);
}
__device__ __forceinline__ unsigned short f2bf(float f) {
  unsigned int u = __float_as_uint(f);
  return (unsigned short)((u + 0x7FFFu + ((u >> 16) & 1u)) >> 16);
}

// ---------------- K0: transpose s; w1 -> bf16 wb1[p][o*32+c], rest -> fp32 wt2 ----------------
__global__ __launch_bounds__(256) void k0_transpose(const float* __restrict__ s,
                                                    unsigned short* __restrict__ wb1,
                                                    float* __restrict__ wt2) {
  __shared__ float tile[64][65];
  const int blk = blockIdx.x;            // b*219 + kt
  const int b  = blk / 219;
  const int kt = blk - b * 219;
  const int k0 = kt * 64;
  const int t  = threadIdx.x;
  {
    const int f  = t & 63;
    const int kr = t >> 6;
    const float* sp = s + ((size_t)b * HYPER + k0 + kr) * 64 + f;
#pragma unroll
    for (int kk = 0; kk < 16; kk++)
      tile[kr + kk * 4][f] = sp[(size_t)kk * 4 * 64];
  }
  __syncthreads();
  {
    const int kk = t & 63;
    const int fr = t >> 6;
    if (kt < 96) {   // w1 region (k < 6144), emit bf16
      unsigned short* wp = wb1 + ((size_t)b * 64 + fr) * W1SZ + k0 + kk;
#pragma unroll
      for (int ff = 0; ff < 16; ff++)
        wp[(size_t)ff * 4 * W1SZ] = f2bf(tile[kk][fr + ff * 4]);
    } else {
      float* wp = wt2 + ((size_t)b * 64 + fr) * WT2SZ + (k0 - W1SZ) + kk;
#pragma unroll
      for (int ff = 0; ff < 16; ff++)
        wp[(size_t)ff * 4 * WT2SZ] = tile[kk][fr + ff * 4];
    }
  }
}

// ---------------- K1: MFMA pointwise 32->192, x1 bf16 [p][o][324], bn1 stats ----------------
__global__ __launch_bounds__(256) void k1_pw1(const float* __restrict__ x,
                                              const unsigned short* __restrict__ wb1,
                                              unsigned short* __restrict__ x1,
                                              float* __restrict__ sums) {
  __shared__ __align__(16) unsigned short pL[21 * 512];   // B frags: 21 ij-tiles
  __shared__ __align__(16) unsigned short wA[12 * 512];   // A frags: 12 o-tiles
  __shared__ float stat[384];
  const int p  = blockIdx.x;
  const int b  = p >> 6;
  const int fi = (p >> 3) & 7;
  const int fj = p & 7;
  const int t  = threadIdx.x;

  for (int i = t; i < 384; i += 256) stat[i] = 0.f;

  // stage w1 frags: value A[o][c], slot ((o>>4)*4 + (c>>3))*128 + (o&15)*8 + (c&7)
  const unsigned short* wbp = wb1 + (size_t)p * W1SZ;
  for (int idx = t; idx < 1536; idx += 256) {     // ushort4 granules
    int o  = idx >> 3;
    int c4 = idx & 7;
    ushort4 v = *(const ushort4*)&wbp[idx * 4];
    int slot = ((o >> 4) * 4 + (c4 >> 1)) * 128 + (o & 15) * 8 + (c4 & 1) * 4;
    *(ushort4*)&wA[slot] = v;
  }
  // stage patch frags: value B[c][ij] = patch[ij][c] (reflect-pad gather)
  const int row0 = fi * 16 - 1, col0 = fj * 16 - 1;
  const float* xb = x + (size_t)b * 32 * 128 * 128;
  for (int idx = t; idx < 32 * A1; idx += 256) {
    int c  = idx / A1;
    int ij = idx - c * A1;
    int ii = ij / 18;
    int jj = ij - ii * 18;
    int r  = row0 + ii; r  = (r  < 0) ? 1 : (r  > 127) ? 126 : r;
    int cl = col0 + jj; cl = (cl < 0) ? 1 : (cl > 127) ? 126 : cl;
    int slot = ((ij >> 4) * 4 + (c >> 3)) * 128 + (ij & 15) * 8 + (c & 7);
    pL[slot] = f2bf(xb[((size_t)c * 128 + r) * 128 + cl]);
  }
  __syncthreads();

  const int lane = t & 63;
  const int wv   = t >> 6;
  const int m16  = lane & 15;
  const int quad = lane >> 4;
  unsigned short* x1p = x1 + (size_t)p * HID * A1;

  for (int oi = 0; oi < 3; oi++) {
    const int ot = wv + oi * 4;                       // 0..11 across 4 waves
    bf16x8 a = *(const bf16x8*)&wA[ot * 512 + lane * 8];
    float sacc[4] = {0.f, 0.f, 0.f, 0.f};
    float qacc[4] = {0.f, 0.f, 0.f, 0.f};
    for (int jt = 0; jt < 21; jt++) {
      bf16x8 bb = *(const bf16x8*)&pL[jt * 512 + lane * 8];
      f32x4 d = __builtin_amdgcn_mfma_f32_16x16x32_bf16(a, bb, (f32x4){0.f, 0.f, 0.f, 0.f}, 0, 0, 0);
      const int ij = jt * 16 + m16;                   // D col = lane&15
      if (ij < A1) {
        unsigned short* dst = x1p + (size_t)(ot * 16 + quad * 4) * A1 + ij;
#pragma unroll
        for (int r = 0; r < 4; r++) {                 // D row = quad*4 + r
          float v = d[r];
          sacc[r] += v;
          qacc[r] = fmaf(v, v, qacc[r]);
          dst[(size_t)r * A1] = f2bf(v);
        }
      }
    }
#pragma unroll
    for (int r = 0; r < 4; r++) {
      float sv = sacc[r], qv = qacc[r];
#pragma unroll
      for (int msk = 1; msk < 16; msk <<= 1) {
        sv += __shfl_xor(sv, msk, 64);
        qv += __shfl_xor(qv, msk, 64);
      }
      if (m16 == 0) {
        int o = ot * 16 + quad * 4 + r;
        atomicAdd(&stat[o], sv);
        atomicAdd(&stat[192 + o], qv);
      }
    }
  }
  __syncthreads();
  for (int i = t; i < 384; i += 256) atomicAdd(&sums[i], stat[i]);
}

// ---------------- K2: bn1+relu6, depthwise 3x3, one 32-channel chunk per block ----------------
// grid: 3072 = chunk(6) * patch(512); x2 bf16 [p][ij][c]; bn2 stats
__global__ __launch_bounds__(256) void k2_dw(const unsigned short* __restrict__ x1,
                                             const float* __restrict__ wt2,
                                             const float* __restrict__ sums,
                                             const float* __restrict__ g1,
                                             const float* __restrict__ b1,
                                             unsigned short* __restrict__ x2,
                                             float* __restrict__ sums2) {
  __shared__ float xc[A1 * 33];     // [ij][32ch + pad]
  __shared__ float w2L[288];
  __shared__ float scc[32], shc[32];
  __shared__ float st2[64];
  const int blk = blockIdx.x;
  const int p  = blk & 511;
  const int cb = (blk >> 9) * 32;
  const int t  = threadIdx.x;
  const float inv = 1.f / 165888.f;    // 512*324
  if (t < 32) {
    int c = cb + t;
    float m   = sums[c] * inv;
    float var = sums[192 + c] * inv - m * m;
    float scl = g1[c] * rsqrtf(var + EPS);
    scc[t] = scl;
    shc[t] = b1[c] - m * scl;
  }
  if (t < 64) st2[t] = 0.f;
  const float* wtp = wt2 + (size_t)p * WT2SZ + (size_t)cb * 9;  // w2 at offset 0
  for (int i = t; i < 288; i += 256) w2L[i] = wtp[i];   // FIX: was `if (t < 288)` with 256 threads
  __syncthreads();
  const unsigned short* x1p = x1 + (size_t)p * HID * A1 + (size_t)cb * A1;
  // stage: consecutive lanes -> consecutive c => conflict-free LDS writes
  for (int idx = t; idx < 2592; idx += 256) {
    int c = idx & 31;
    int g = idx >> 5;        // 0..80
    ushort4 uv = *(const ushort4*)&x1p[(size_t)c * A1 + g * 4];
    float scl = scc[c], shv = shc[c];
    int ij = g * 4;
    xc[(ij + 0) * 33 + c] = relu6f(fmaf(bf2f(uv.x), scl, shv));
    xc[(ij + 1) * 33 + c] = relu6f(fmaf(bf2f(uv.y), scl, shv));
    xc[(ij + 2) * 33 + c] = relu6f(fmaf(bf2f(uv.z), scl, shv));
    xc[(ij + 3) * 33 + c] = relu6f(fmaf(bf2f(uv.w), scl, shv));
  }
  __syncthreads();
  const int cc = t & 31;
  const int jb = t >> 5;   // 0..7
  unsigned short* x2p = x2 + (size_t)p * A2 * HID;
  float wr[9];
#pragma unroll
  for (int uv = 0; uv < 9; uv++) wr[uv] = w2L[cc * 9 + uv];
  float ls = 0.f, lq = 0.f;
#pragma unroll
  for (int it = 0; it < 2; it++) {
    const int j = jb + it * 8;
    float accs[20];
#pragma unroll
    for (int i = 0; i < 20; i++) accs[i] = 0.f;
#pragma unroll
    for (int r = 0; r < 18; r++) {
      const float* base = &xc[(r * 18 + j) * 33 + cc];
      float v0 = base[0], v1 = base[33], v2 = base[66];
#pragma unroll
      for (int u = 0; u < 3; u++) {
        float a = accs[r - u + 2];
        a = fmaf(v0, wr[u * 3 + 0], a);
        a = fmaf(v1, wr[u * 3 + 1], a);
        a = fmaf(v2, wr[u * 3 + 2], a);
        accs[r - u + 2] = a;
      }
    }
#pragma unroll
    for (int i = 0; i < 16; i++) {
      unsigned int h = f2bf(accs[i + 2]);
      float rv = bf2f(h);
      ls += rv;
      lq = fmaf(rv, rv, lq);
      x2p[(size_t)(i * 16 + j) * HID + cb + cc] = (unsigned short)h;
    }
  }
  // lanes l and l^32 share cc: fold once, then 32 atomic lanes per wave
  ls += __shfl_xor(ls, 32, 64);
  lq += __shfl_xor(lq, 32, 64);
  if ((t & 32) == 0) {
    atomicAdd(&st2[cc], ls);
    atomicAdd(&st2[32 + cc], lq);
  }
  __syncthreads();
  if (t < 32) atomicAdd(&sums2[cb + t], st2[t]);
  else if (t < 64) atomicAdd(&sums2[192 + cb + (t - 32)], st2[t]);
}

// ---------------- K3: MFMA pointwise 192->32, bn2+relu6 fused on B-load ----------------
// grid: 1024 = patch(512) * ij-half(2); x3 fp32 [p][o][256]; bn3 stats
__global__ __launch_bounds__(256) void k3_pw2(const unsigned short* __restrict__ x2,
                                              const float* __restrict__ wt2,
                                              const float* __restrict__ sums2,
                                              const float* __restrict__ g2,
                                              const float* __restrict__ b2,
                                              float* __restrict__ x3,
                                              float* __restrict__ sums3) {
  __shared__ __align__(16) unsigned short wA[12 * 512];   // A frags: [ot(2)][ks(6)]
  __shared__ float sc[HID], sh[HID];
  __shared__ float st3[64];
  const int blk  = blockIdx.x;
  const int p    = blk >> 1;
  const int half = blk & 1;
  const int t    = threadIdx.x;
  const float inv = 1.f / 131072.f;   // 512*256
  for (int c = t; c < HID; c += 256) {
    float m   = sums2[c] * inv;
    float var = sums2[192 + c] * inv - m * m;
    float scl = g2[c] * rsqrtf(var + EPS);
    sc[c] = scl;
    sh[c] = b2[c] - m * scl;
  }
  if (t < 64) st3[t] = 0.f;
  // stage w3 -> bf16 A-frags: A[m=o&15][k], frag (ot=o>>4, ks=c>>5)
  const float* w3p = wt2 + (size_t)p * WT2SZ + R3OFF;     // [o][192]
  for (int idx = t; idx < 32 * 48; idx += 256) {
    int o  = idx / 48;
    int c4 = idx - o * 48;
    float4 v = *(const float4*)&w3p[o * HID + c4 * 4];
    int slot = ((o >> 4) * 6 + (c4 >> 3)) * 512 + ((((c4 >> 1) & 3) * 16) + (o & 15)) * 8 + (c4 & 1) * 4;
    ushort4 u;
    u.x = f2bf(v.x); u.y = f2bf(v.y); u.z = f2bf(v.z); u.w = f2bf(v.w);
    *(ushort4*)&wA[slot] = u;
  }
  __syncthreads();
  const int lane = t & 63;
  const int wv   = t >> 6;
  const int m16  = lane & 15;
  const int kg   = lane >> 4;
  bf16x8 aF[2][6];
#pragma unroll
  for (int ot = 0; ot < 2; ot++)
#pragma unroll
    for (int ks = 0; ks < 6; ks++)
      aF[ot][ks] = *(const bf16x8*)&wA[(ot * 6 + ks) * 512 + lane * 8];
  const unsigned short* x2p = x2 + (size_t)p * A2 * HID;
  f32x4 acc[2][2];
#pragma unroll
  for (int it = 0; it < 2; it++)
#pragma unroll
    for (int ot = 0; ot < 2; ot++)
#pragma unroll
      for (int r = 0; r < 4; r++) acc[it][ot][r] = 0.f;
#pragma unroll
  for (int it = 0; it < 2; it++) {
    const int ijt = half * 8 + wv + it * 4;
    const int ij  = ijt * 16 + m16;
    const unsigned short* brow = x2p + (size_t)ij * HID + kg * 8;
#pragma unroll
    for (int ks = 0; ks < 6; ks++) {
      ushort4 u0 = *(const ushort4*)&brow[ks * 32];
      ushort4 u1 = *(const ushort4*)&brow[ks * 32 + 4];
      const float* scp = &sc[ks * 32 + kg * 8];
      const float* shp = &sh[ks * 32 + kg * 8];
      unsigned short uu[8] = {u0.x, u0.y, u0.z, u0.w, u1.x, u1.y, u1.z, u1.w};
      bf16x8 bb;
#pragma unroll
      for (int j = 0; j < 8; j++) {
        float y = relu6f(fmaf(bf2f(uu[j]), scp[j], shp[j]));
        bb[j] = (short)f2bf(y);
      }
      acc[it][0] = __builtin_amdgcn_mfma_f32_16x16x32_bf16(aF[0][ks], bb, acc[it][0], 0, 0, 0);
      acc[it][1] = __builtin_amdgcn_mfma_f32_16x16x32_bf16(aF[1][ks], bb, acc[it][1], 0, 0, 0);
    }
  }
  float* x3p = x3 + (size_t)p * 32 * A2;
  float sacc[2][4] = {{0.f}}, qacc[2][4] = {{0.f}};
#pragma unroll
  for (int it = 0; it < 2; it++) {
    const int ijt = half * 8 + wv + it * 4;
#pragma unroll
    for (int ot = 0; ot < 2; ot++) {
#pragma unroll
      for (int r = 0; r < 4; r++) {
        float v = acc[it][ot][r];
        x3p[(size_t)(ot * 16 + kg * 4 + r) * A2 + ijt * 16 + m16] = v;
        sacc[ot][r] += v;
        qacc[ot][r] = fmaf(v, v, qacc[ot][r]);
      }
    }
  }
#pragma unroll
  for (int ot = 0; ot < 2; ot++)
#pragma unroll
    for (int r = 0; r < 4; r++) {
      float sv = sacc[ot][r], qv = qacc[ot][r];
#pragma unroll
      for (int msk = 1; msk < 16; msk <<= 1) {
        sv += __shfl_xor(sv, msk, 64);
        qv += __shfl_xor(qv, msk, 64);
      }
      if (m16 == 0) {
        int o = ot * 16 + kg * 4 + r;
        atomicAdd(&st3[o], sv);
        atomicAdd(&st3[32 + o], qv);
      }
    }
  __syncthreads();
  if (t < 64) atomicAdd(&sums3[t], st3[t]);
}

// ---------------- K4: bn3 + residual + layout transform ----------------
__global__ __launch_bounds__(256) void k4_out(const float* __restrict__ x,
                                              const float* __restrict__ x3,
                                              const float* __restrict__ sums3,
                                              const float* __restrict__ g3,
                                              const float* __restrict__ b3,
                                              float* __restrict__ out) {
  const int idx4 = blockIdx.x * 256 + threadIdx.x;   // 1,048,576 float4 total
  const int w4 = idx4 & 31;
  int tmp = idx4 >> 5;
  const int h = tmp & 127; tmp >>= 7;
  const int o = tmp & 31;
  const int b = tmp >> 5;
  const int fi = h >> 4, i = h & 15;
  const int fj = w4 >> 2;
  const int j0 = (w4 & 3) * 4;
  const int p   = b * 64 + fi * 8 + fj;
  const int ij0 = i * 16 + j0;
  const float inv = 1.f / 131072.f;
  float m   = sums3[o] * inv;
  float var = sums3[32 + o] * inv - m * m;
  float sv  = g3[o] * rsqrtf(var + EPS);
  float shv = b3[o] - m * sv;
  float4 xv = *(const float4*)&x[(size_t)idx4 * 4];
  float4 v  = *(const float4*)&x3[((size_t)p * 32 + o) * A2 + ij0];
  float4 r;
  r.x = fmaf(v.x, sv, shv) + xv.x;
  r.y = fmaf(v.y, sv, shv) + xv.y;
  r.z = fmaf(v.z, sv, shv) + xv.z;
  r.w = fmaf(v.w, sv, shv) + xv.w;
  *(float4*)&out[(size_t)idx4 * 4] = r;
}

extern "C" void kernel_launch(void* const* d_in, const int* in_sizes, int n_in,
                              void* d_out, int out_size, void* d_ws, size_t ws_size,
                              hipStream_t stream) {
  const float* x  = (const float*)d_in[0];
  const float* s  = (const float*)d_in[1];
  const float* g1 = (const float*)d_in[2];
  const float* b1 = (const float*)d_in[3];
  const float* g2 = (const float*)d_in[4];
  const float* b2 = (const float*)d_in[5];
  const float* g3 = (const float*)d_in[6];
  const float* b3 = (const float*)d_in[7];
  char* base = (char*)d_ws;
  unsigned short* wb1  = (unsigned short*)(base + WB1_B);
  float*          wt2  = (float*)(base + WT2_B);
  unsigned short* x1   = (unsigned short*)(base + X1_B);
  unsigned short* x2   = (unsigned short*)(base + X2_B);
  float*          x3   = (float*)(base + X3_B);
  float*          sums = (float*)(base + SUM_B);
  float* out = (float*)d_out;

  hipMemsetAsync(sums, 0, 832 * sizeof(float), stream);
  k0_transpose<<<8 * 219, 256, 0, stream>>>(s, wb1, wt2);
  k1_pw1<<<P_TOT, 256, 0, stream>>>(x, wb1, x1, sums);
  k2_dw<<<3072, 256, 0, stream>>>(x1, wt2, sums, g1, b1, x2, sums + 384);
  k3_pw2<<<1024, 256, 0, stream>>>(x2, wt2, sums + 384, g2, b2, x3, sums + 768);
  k4_out<<<4096, 256, 0, stream>>>(x, x3, sums + 768, g3, b3, out);
}

// Round 7
// 222.972 us; speedup vs baseline: 1.6267x; 1.0572x over previous
//
#include <hip/hip_runtime.h>

#define EPS 1e-5f

namespace {
constexpr int HYPER = 14016;
constexpr int HID   = 192;
constexpr int A1    = 324;   // 18*18
constexpr int A2    = 256;   // 16*16
constexpr int P_TOT = 512;
constexpr int W1SZ  = 6144;  // 32*192
constexpr int WT2SZ = 7872;  // w2 (1728) + w3 (6144)
constexpr int R3OFF = 1728;  // w3 offset inside wt2

// workspace byte offsets
constexpr size_t WB1_B = 0;                       // bf16 w1 A-frag order [p][6144], 6,291,456 B
constexpr size_t WT2_B = 6291456;                 // fp32 w2+w3 [p][7872], 16,121,856 B
constexpr size_t X2_B  = WT2_B + 16121856;        // bf16 x2 [p][12][256][16], 50,331,648 B
constexpr size_t X3_B  = X2_B + 50331648;         // fp32 x3 [p][32][256], 16,777,216 B
constexpr size_t SUM_B = X3_B + 16777216;         // fp32 832 floats
// sums: [0:192) s1 [192:384) q1 [384:576) s2 [576:768) q2 [768:800) s3 [800:832) q3
}

typedef __attribute__((ext_vector_type(8))) short bf16x8;
typedef __attribute__((ext_vector_type(4))) float f32x4;

__device__ __forceinline__ float relu6f(float v) { return fminf(fmaxf(v, 0.f), 6.f); }

__device__ __forceinline__ float bf2f(unsigned int h) {
  return __uint_as_float(h << 16);
}
__device__ __forceinline__ unsigned short f2bf(float f) {
  unsigned int u = __float_as_uint(f);
  return (unsigned short)((u + 0x7FFFu + ((u >> 16) & 1u)) >> 16);
}

// A-frag slot for element w1[o][c] (o<192, c<32), 16x16x32 MFMA:
// lane = (c>>3)*16 + (o&15), j = c&7  ->  slot = (o>>4)*512 + lane*8 + j
__device__ __host__ __forceinline__ int afrag_slot(int o, int c) {
  return (o >> 4) * 512 + (c >> 3) * 128 + (o & 15) * 8 + (c & 7);
}

// ---------------- K0: transpose s; w1 -> bf16 wb1 (A-frag order), rest -> fp32 wt2 ----------------
__global__ __launch_bounds__(256) void k0_transpose(const float* __restrict__ s,
                                                    unsigned short* __restrict__ wb1,
                                                    float* __restrict__ wt2) {
  __shared__ float tile[64][65];
  const int blk = blockIdx.x;            // b*219 + kt
  const int b  = blk / 219;
  const int kt = blk - b * 219;
  const int k0 = kt * 64;
  const int t  = threadIdx.x;
  {
    const int f  = t & 63;
    const int kr = t >> 6;
    const float* sp = s + ((size_t)b * HYPER + k0 + kr) * 64 + f;
#pragma unroll
    for (int kk = 0; kk < 16; kk++)
      tile[kr + kk * 4][f] = sp[(size_t)kk * 4 * 64];
  }
  __syncthreads();
  {
    const int kk = t & 63;
    const int fr = t >> 6;
    if (kt < 96) {   // w1 region (k < 6144): emit bf16 in A-frag order
      const int k = k0 + kk;
      const int o = k >> 5, c = k & 31;
      const int slot = afrag_slot(o, c);
      unsigned short* wp = wb1 + ((size_t)b * 64 + fr) * W1SZ + slot;
#pragma unroll
      for (int ff = 0; ff < 16; ff++)
        wp[(size_t)ff * 4 * W1SZ] = f2bf(tile[kk][fr + ff * 4]);
    } else {
      float* wp = wt2 + ((size_t)b * 64 + fr) * WT2SZ + (k0 - W1SZ) + kk;
#pragma unroll
      for (int ff = 0; ff < 16; ff++)
        wp[(size_t)ff * 4 * WT2SZ] = tile[kk][fr + ff * 4];
    }
  }
}

// ---------------- K1: MFMA conv1, bn1 stats ONLY (no x1 materialization) ----------------
__global__ __launch_bounds__(256) void k1_stats(const float* __restrict__ x,
                                                const unsigned short* __restrict__ wb1,
                                                float* __restrict__ sums) {
  __shared__ __align__(16) unsigned short pL[21 * 512];   // B frags: 21 ij-tiles
  __shared__ float stat[384];
  const int p  = blockIdx.x;
  const int b  = p >> 6;
  const int fi = (p >> 3) & 7;
  const int fj = p & 7;
  const int t  = threadIdx.x;

  for (int i = t; i < 384; i += 256) stat[i] = 0.f;

  // stage patch frags: value B[c][ij] = patch[ij][c] (reflect-pad gather)
  const int row0 = fi * 16 - 1, col0 = fj * 16 - 1;
  const float* xb = x + (size_t)b * 32 * 128 * 128;
  for (int idx = t; idx < 32 * A1; idx += 256) {
    int c  = idx / A1;
    int ij = idx - c * A1;
    int ii = ij / 18;
    int jj = ij - ii * 18;
    int r  = row0 + ii; r  = (r  < 0) ? 1 : (r  > 127) ? 126 : r;
    int cl = col0 + jj; cl = (cl < 0) ? 1 : (cl > 127) ? 126 : cl;
    int slot = ((ij >> 4) * 4 + (c >> 3)) * 128 + (ij & 15) * 8 + (c & 7);
    pL[slot] = f2bf(xb[((size_t)c * 128 + r) * 128 + cl]);
  }
  __syncthreads();

  const int lane = t & 63;
  const int wv   = t >> 6;
  const int m16  = lane & 15;
  const int quad = lane >> 4;
  const unsigned short* wbp = wb1 + (size_t)p * W1SZ;

  for (int oi = 0; oi < 3; oi++) {
    const int ot = wv + oi * 4;                       // 0..11 across 4 waves
    bf16x8 a = *(const bf16x8*)(wbp + ot * 512 + lane * 8);   // pre-swizzled global
    float sacc[4] = {0.f, 0.f, 0.f, 0.f};
    float qacc[4] = {0.f, 0.f, 0.f, 0.f};
    for (int jt = 0; jt < 21; jt++) {
      bf16x8 bb = *(const bf16x8*)&pL[jt * 512 + lane * 8];
      f32x4 d = __builtin_amdgcn_mfma_f32_16x16x32_bf16(a, bb, (f32x4){0.f, 0.f, 0.f, 0.f}, 0, 0, 0);
      const int ij = jt * 16 + m16;                   // D col = lane&15
      if (ij < A1) {
#pragma unroll
        for (int r = 0; r < 4; r++) {                 // D row = quad*4 + r
          float v = d[r];                             // raw fp32 (k2 recomputes same)
          sacc[r] += v;
          qacc[r] = fmaf(v, v, qacc[r]);
        }
      }
    }
#pragma unroll
    for (int r = 0; r < 4; r++) {
      float sv = sacc[r], qv = qacc[r];
#pragma unroll
      for (int msk = 1; msk < 16; msk <<= 1) {
        sv += __shfl_xor(sv, msk, 64);
        qv += __shfl_xor(qv, msk, 64);
      }
      if (m16 == 0) {
        int o = ot * 16 + quad * 4 + r;
        atomicAdd(&stat[o], sv);
        atomicAdd(&stat[192 + o], qv);
      }
    }
  }
  __syncthreads();
  for (int i = t; i < 384; i += 256) atomicAdd(&sums[i], stat[i]);
}

// ---------------- K2: fused conv1-recompute + bn1 + relu6 + depthwise 3x3 + bn2 stats ----
// grid: 512 (one patch per block). x2 layout [p][12 ot][256 ij][16 c] bf16.
// 6 rounds x 2 o-tiles; per round each tile's conv1 is split across two waves (jt halves).
__global__ __launch_bounds__(256) void k2_fused(const float* __restrict__ x,
                                                const unsigned short* __restrict__ wb1,
                                                const float* __restrict__ wt2,
                                                const float* __restrict__ sums,
                                                const float* __restrict__ g1,
                                                const float* __restrict__ b1,
                                                unsigned short* __restrict__ x2,
                                                float* __restrict__ sums2) {
  __shared__ __align__(16) unsigned short pL[21 * 512];      // 21504 B
  __shared__ __align__(16) unsigned short xc[2][324 * 18];   // 23328 B (pad-18 c rows)
  __shared__ __align__(16) unsigned short x2s[256 * 18];     //  9216 B
  __shared__ float sc[HID], sh[HID];                         //  1536 B
  __shared__ float st2[384];                                 //  1536 B  => 57120 B total
  const int p  = blockIdx.x;
  const int b  = p >> 6;
  const int fi = (p >> 3) & 7;
  const int fj = p & 7;
  const int t  = threadIdx.x;

  const float inv1 = 1.f / 165888.f;    // 512*324
  for (int c = t; c < HID; c += 256) {
    float m   = sums[c] * inv1;
    float var = sums[192 + c] * inv1 - m * m;
    float scl = g1[c] * rsqrtf(var + EPS);
    sc[c] = scl;
    sh[c] = b1[c] - m * scl;
  }
  for (int i = t; i < 384; i += 256) st2[i] = 0.f;

  // stage patch B-frags (identical to k1)
  const int row0 = fi * 16 - 1, col0 = fj * 16 - 1;
  const float* xb = x + (size_t)b * 32 * 128 * 128;
  for (int idx = t; idx < 32 * A1; idx += 256) {
    int c  = idx / A1;
    int ij = idx - c * A1;
    int ii = ij / 18;
    int jj = ij - ii * 18;
    int r  = row0 + ii; r  = (r  < 0) ? 1 : (r  > 127) ? 126 : r;
    int cl = col0 + jj; cl = (cl < 0) ? 1 : (cl > 127) ? 126 : cl;
    int slot = ((ij >> 4) * 4 + (c >> 3)) * 128 + (ij & 15) * 8 + (c & 7);
    pL[slot] = f2bf(xb[((size_t)c * 128 + r) * 128 + cl]);
  }
  __syncthreads();

  const int lane = t & 63;
  const int wv   = t >> 6;
  const int m16  = lane & 15;
  const int quad = lane >> 4;
  const int cdw  = t >> 4;    // 0..15 dw channel-within-tile
  const int jdw  = t & 15;    // 0..15 dw output col
  const float* w2p = wt2 + (size_t)p * WT2SZ;   // [192][9] fp32
  unsigned short* x2base = x2 + (size_t)p * 12 * 4096;
  const unsigned short* wbp = wb1 + (size_t)p * W1SZ;

  for (int ri = 0; ri < 6; ri++) {
    // ---- conv1 MFMA: tile (wv&1), jt-half (wv>>1); A-frags from pre-swizzled global ----
    const int sub = wv & 1;
    const int ot  = ri * 2 + sub;
    const int jt0 = (wv >> 1) * 11;          // 0 or 11
    const int jt1 = jt0 + 11 - (wv >> 1);    // 11 or 21
    bf16x8 a = *(const bf16x8*)(wbp + ot * 512 + lane * 8);
    for (int jt = jt0; jt < jt1; jt++) {
      bf16x8 bb = *(const bf16x8*)&pL[jt * 512 + lane * 8];
      f32x4 d = __builtin_amdgcn_mfma_f32_16x16x32_bf16(a, bb, (f32x4){0.f, 0.f, 0.f, 0.f}, 0, 0, 0);
      const int ij = jt * 16 + m16;
      if (ij < A1) {
        unsigned short* xcp = &xc[sub][ij * 18 + quad * 4];
#pragma unroll
        for (int r = 0; r < 4; r++) {
          int ch = ot * 16 + quad * 4 + r;
          float v = relu6f(fmaf(d[r], sc[ch], sh[ch]));
          xcp[r] = f2bf(v);
        }
      }
    }
    __syncthreads();
    // ---- depthwise per tile: 256 threads = 16c x 16j ----
    for (int sub2 = 0; sub2 < 2; sub2++) {
      const int ot2 = ri * 2 + sub2;
      const int ch  = ot2 * 16 + cdw;
      float wr[9];
#pragma unroll
      for (int u = 0; u < 9; u++) wr[u] = w2p[ch * 9 + u];
      float accs[16];
#pragma unroll
      for (int i = 0; i < 16; i++) accs[i] = 0.f;
      const unsigned short* xcs = &xc[sub2][0];
#pragma unroll
      for (int r = 0; r < 18; r++) {
        const unsigned short* bp = &xcs[(r * 18 + jdw) * 18 + cdw];
        float v0 = bf2f(bp[0]);
        float v1 = bf2f(bp[18]);
        float v2 = bf2f(bp[36]);
#pragma unroll
        for (int u = 0; u < 3; u++) {
          int i = r - u;
          if (i >= 0 && i < 16)
            accs[i] = fmaf(v0, wr[u * 3 + 0],
                      fmaf(v1, wr[u * 3 + 1],
                      fmaf(v2, wr[u * 3 + 2], accs[i])));
        }
      }
      float ls = 0.f, lq = 0.f;
#pragma unroll
      for (int i = 0; i < 16; i++) {
        unsigned short h = f2bf(accs[i]);
        float rv = bf2f(h);
        ls += rv;
        lq = fmaf(rv, rv, lq);
        x2s[(i * 16 + jdw) * 18 + cdw] = h;
      }
#pragma unroll
      for (int msk = 1; msk < 16; msk <<= 1) {
        ls += __shfl_xor(ls, msk, 64);
        lq += __shfl_xor(lq, msk, 64);
      }
      if (jdw == 0) {
        atomicAdd(&st2[ch], ls);
        atomicAdd(&st2[192 + ch], lq);
      }
      __syncthreads();
      // coop store: 4096 ushorts contiguous -> x2[p][ot2][ij][16]
      unsigned short* dst = x2base + (size_t)ot2 * 4096;
#pragma unroll
      for (int k = 0; k < 4; k++) {
        int g  = (k * 256 + t) * 4;          // ushort offset, multiple of 4
        int ij = g >> 4, c0 = g & 15;
        unsigned int a0 = *(const unsigned int*)&x2s[ij * 18 + c0];
        unsigned int a1 = *(const unsigned int*)&x2s[ij * 18 + c0 + 2];
        uint2 v; v.x = a0; v.y = a1;
        *(uint2*)&dst[g] = v;
      }
      __syncthreads();
    }
  }
  for (int i = t; i < 384; i += 256) atomicAdd(&sums2[i], st2[i]);
}

// ---------------- K3: MFMA pointwise 192->32, bn2+relu6 fused on B-load ----------------
// grid: 1024 = patch(512) * ij-half(2); x3 fp32 [p][o][256]; bn3 stats
__global__ __launch_bounds__(256) void k3_pw2(const unsigned short* __restrict__ x2,
                                              const float* __restrict__ wt2,
                                              const float* __restrict__ sums2,
                                              const float* __restrict__ g2,
                                              const float* __restrict__ b2,
                                              float* __restrict__ x3,
                                              float* __restrict__ sums3) {
  __shared__ __align__(16) unsigned short wA[12 * 512];   // A frags: [ot(2)][ks(6)]
  __shared__ float sc[HID], sh[HID];
  __shared__ float st3[64];
  const int blk  = blockIdx.x;
  const int p    = blk >> 1;
  const int half = blk & 1;
  const int t    = threadIdx.x;
  const float inv = 1.f / 131072.f;   // 512*256
  for (int c = t; c < HID; c += 256) {
    float m   = sums2[c] * inv;
    float var = sums2[192 + c] * inv - m * m;
    float scl = g2[c] * rsqrtf(var + EPS);
    sc[c] = scl;
    sh[c] = b2[c] - m * scl;
  }
  if (t < 64) st3[t] = 0.f;
  // stage w3 -> bf16 A-frags: A[m=o&15][k], frag (ot=o>>4, ks=c>>5)
  const float* w3p = wt2 + (size_t)p * WT2SZ + R3OFF;     // [o][192]
  for (int idx = t; idx < 32 * 48; idx += 256) {
    int o  = idx / 48;
    int c4 = idx - o * 48;
    float4 v = *(const float4*)&w3p[o * HID + c4 * 4];
    int slot = ((o >> 4) * 6 + (c4 >> 3)) * 512 + ((((c4 >> 1) & 3) * 16) + (o & 15)) * 8 + (c4 & 1) * 4;
    ushort4 u;
    u.x = f2bf(v.x); u.y = f2bf(v.y); u.z = f2bf(v.z); u.w = f2bf(v.w);
    *(ushort4*)&wA[slot] = u;
  }
  __syncthreads();
  const int lane = t & 63;
  const int wv   = t >> 6;
  const int m16  = lane & 15;
  const int kg   = lane >> 4;
  bf16x8 aF[2][6];
#pragma unroll
  for (int ot = 0; ot < 2; ot++)
#pragma unroll
    for (int ks = 0; ks < 6; ks++)
      aF[ot][ks] = *(const bf16x8*)&wA[(ot * 6 + ks) * 512 + lane * 8];
  const unsigned short* x2p = x2 + (size_t)p * 12 * 4096;
  f32x4 acc[2][2];
#pragma unroll
  for (int it = 0; it < 2; it++)
#pragma unroll
    for (int ot = 0; ot < 2; ot++)
#pragma unroll
      for (int r = 0; r < 4; r++) acc[it][ot][r] = 0.f;
#pragma unroll
  for (int it = 0; it < 2; it++) {
    const int ijt = half * 8 + wv + it * 4;
    const int ij  = ijt * 16 + m16;
    // x2 [ot12][ij][16]: for k = ks*32 + kg*8 + j, addr = ks*8192 + (kg>>1)*4096 + ij*16 + (kg&1)*8
    const unsigned short* brow = x2p + (size_t)(kg >> 1) * 4096 + (size_t)ij * 16 + (kg & 1) * 8;
#pragma unroll
    for (int ks = 0; ks < 6; ks++) {
      ushort4 u0 = *(const ushort4*)&brow[ks * 8192];
      ushort4 u1 = *(const ushort4*)&brow[ks * 8192 + 4];
      const float* scp = &sc[ks * 32 + kg * 8];
      const float* shp = &sh[ks * 32 + kg * 8];
      unsigned short uu[8] = {u0.x, u0.y, u0.z, u0.w, u1.x, u1.y, u1.z, u1.w};
      bf16x8 bb;
#pragma unroll
      for (int j = 0; j < 8; j++) {
        float y = relu6f(fmaf(bf2f(uu[j]), scp[j], shp[j]));
        bb[j] = (short)f2bf(y);
      }
      acc[it][0] = __builtin_amdgcn_mfma_f32_16x16x32_bf16(aF[0][ks], bb, acc[it][0], 0, 0, 0);
      acc[it][1] = __builtin_amdgcn_mfma_f32_16x16x32_bf16(aF[1][ks], bb, acc[it][1], 0, 0, 0);
    }
  }
  float* x3p = x3 + (size_t)p * 32 * A2;
  float sacc[2][4] = {{0.f}}, qacc[2][4] = {{0.f}};
#pragma unroll
  for (int it = 0; it < 2; it++) {
    const int ijt = half * 8 + wv + it * 4;
#pragma unroll
    for (int ot = 0; ot < 2; ot++) {
#pragma unroll
      for (int r = 0; r < 4; r++) {
        float v = acc[it][ot][r];
        x3p[(size_t)(ot * 16 + kg * 4 + r) * A2 + ijt * 16 + m16] = v;
        sacc[ot][r] += v;
        qacc[ot][r] = fmaf(v, v, qacc[ot][r]);
      }
    }
  }
#pragma unroll
  for (int ot = 0; ot < 2; ot++)
#pragma unroll
    for (int r = 0; r < 4; r++) {
      float sv = sacc[ot][r], qv = qacc[ot][r];
#pragma unroll
      for (int msk = 1; msk < 16; msk <<= 1) {
        sv += __shfl_xor(sv, msk, 64);
        qv += __shfl_xor(qv, msk, 64);
      }
      if (m16 == 0) {
        int o = ot * 16 + kg * 4 + r;
        atomicAdd(&st3[o], sv);
        atomicAdd(&st3[32 + o], qv);
      }
    }
  __syncthreads();
  if (t < 64) atomicAdd(&sums3[t], st3[t]);
}

// ---------------- K4: bn3 + residual + layout transform ----------------
__global__ __launch_bounds__(256) void k4_out(const float* __restrict__ x,
                                              const float* __restrict__ x3,
                                              const float* __restrict__ sums3,
                                              const float* __restrict__ g3,
                                              const float* __restrict__ b3,
                                              float* __restrict__ out) {
  const int idx4 = blockIdx.x * 256 + threadIdx.x;   // 1,048,576 float4 total
  const int w4 = idx4 & 31;
  int tmp = idx4 >> 5;
  const int h = tmp & 127; tmp >>= 7;
  const int o = tmp & 31;
  const int b = tmp >> 5;
  const int fi = h >> 4, i = h & 15;
  const int fj = w4 >> 2;
  const int j0 = (w4 & 3) * 4;
  const int p   = b * 64 + fi * 8 + fj;
  const int ij0 = i * 16 + j0;
  const float inv = 1.f / 131072.f;
  float m   = sums3[o] * inv;
  float var = sums3[32 + o] * inv - m * m;
  float sv  = g3[o] * rsqrtf(var + EPS);
  float shv = b3[o] - m * sv;
  float4 xv = *(const float4*)&x[(size_t)idx4 * 4];
  float4 v  = *(const float4*)&x3[((size_t)p * 32 + o) * A2 + ij0];
  float4 r;
  r.x = fmaf(v.x, sv, shv) + xv.x;
  r.y = fmaf(v.y, sv, shv) + xv.y;
  r.z = fmaf(v.z, sv, shv) + xv.z;
  r.w = fmaf(v.w, sv, shv) + xv.w;
  *(float4*)&out[(size_t)idx4 * 4] = r;
}

extern "C" void kernel_launch(void* const* d_in, const int* in_sizes, int n_in,
                              void* d_out, int out_size, void* d_ws, size_t ws_size,
                              hipStream_t stream) {
  const float* x  = (const float*)d_in[0];
  const float* s  = (const float*)d_in[1];
  const float* g1 = (const float*)d_in[2];
  const float* b1 = (const float*)d_in[3];
  const float* g2 = (const float*)d_in[4];
  const float* b2 = (const float*)d_in[5];
  const float* g3 = (const float*)d_in[6];
  const float* b3 = (const float*)d_in[7];
  char* base = (char*)d_ws;
  unsigned short* wb1  = (unsigned short*)(base + WB1_B);
  float*          wt2  = (float*)(base + WT2_B);
  unsigned short* x2   = (unsigned short*)(base + X2_B);
  float*          x3   = (float*)(base + X3_B);
  float*          sums = (float*)(base + SUM_B);
  float* out = (float*)d_out;

  hipMemsetAsync(sums, 0, 832 * sizeof(float), stream);
  k0_transpose<<<8 * 219, 256, 0, stream>>>(s, wb1, wt2);
  k1_stats<<<P_TOT, 256, 0, stream>>>(x, wb1, sums);
  k2_fused<<<P_TOT, 256, 0, stream>>>(x, wb1, wt2, sums, g1, b1, x2, sums + 384);
  k3_pw2<<<1024, 256, 0, stream>>>(x2, wt2, sums + 384, g2, b2, x3, sums + 768);
  k4_out<<<4096, 256, 0, stream>>>(x, x3, sums + 768, g3, b3, out);
}

// Round 8
// 221.028 us; speedup vs baseline: 1.6410x; 1.0088x over previous
//
#include <hip/hip_runtime.h>

#define EPS 1e-5f

namespace {
constexpr int HYPER = 14016;
constexpr int HID   = 192;
constexpr int A1    = 324;   // 18*18
constexpr int A2    = 256;   // 16*16
constexpr int P_TOT = 512;
constexpr int W1SZ  = 6144;  // 32*192
constexpr int WT2SZ = 7872;  // w2 (1728) + w3 (6144)
constexpr int R3OFF = 1728;  // w3 offset inside wt2

// workspace byte offsets
constexpr size_t WB1_B = 0;                       // bf16 w1 A-frag order [p][6144], 6,291,456 B
constexpr size_t WT2_B = 6291456;                 // fp32 w2+w3 [p][7872], 16,121,856 B
constexpr size_t X2_B  = WT2_B + 16121856;        // bf16 x2 [p][12][256][16], 50,331,648 B
constexpr size_t X3_B  = X2_B + 50331648;         // bf16 x3 [p][32][256], 8,388,608 B
constexpr size_t SUM_B = X3_B + 8388608;          // fp32 832 floats
// sums: [0:192) s1 [192:384) q1 [384:576) s2 [576:768) q2 [768:800) s3 [800:832) q3
}

typedef __attribute__((ext_vector_type(8))) short bf16x8;
typedef __attribute__((ext_vector_type(4))) float f32x4;

__device__ __forceinline__ float relu6f(float v) { return fminf(fmaxf(v, 0.f), 6.f); }

__device__ __forceinline__ float bf2f(unsigned int h) {
  return __uint_as_float(h << 16);
}
__device__ __forceinline__ unsigned short f2bf(float f) {
  unsigned int u = __float_as_uint(f);
  return (unsigned short)((u + 0x7FFFu + ((u >> 16) & 1u)) >> 16);
}

// A-frag slot for element w1[o][c] (o<192, c<32), 16x16x32 MFMA:
// lane = (c>>3)*16 + (o&15), j = c&7  ->  slot = (o>>4)*512 + lane*8 + j
__device__ __host__ __forceinline__ int afrag_slot(int o, int c) {
  return (o >> 4) * 512 + (c >> 3) * 128 + (o & 15) * 8 + (c & 7);
}

// ---------------- K0: transpose s; w1 -> bf16 wb1 (A-frag order), rest -> fp32 wt2 ----------------
__global__ __launch_bounds__(256) void k0_transpose(const float* __restrict__ s,
                                                    unsigned short* __restrict__ wb1,
                                                    float* __restrict__ wt2) {
  __shared__ float tile[64][65];
  const int blk = blockIdx.x;            // b*219 + kt
  const int b  = blk / 219;
  const int kt = blk - b * 219;
  const int k0 = kt * 64;
  const int t  = threadIdx.x;
  {
    const int f  = t & 63;
    const int kr = t >> 6;
    const float* sp = s + ((size_t)b * HYPER + k0 + kr) * 64 + f;
#pragma unroll
    for (int kk = 0; kk < 16; kk++)
      tile[kr + kk * 4][f] = sp[(size_t)kk * 4 * 64];
  }
  __syncthreads();
  {
    const int kk = t & 63;
    const int fr = t >> 6;
    if (kt < 96) {   // w1 region (k < 6144): emit bf16 in A-frag order
      const int k = k0 + kk;
      const int o = k >> 5, c = k & 31;
      const int slot = afrag_slot(o, c);
      unsigned short* wp = wb1 + ((size_t)b * 64 + fr) * W1SZ + slot;
#pragma unroll
      for (int ff = 0; ff < 16; ff++)
        wp[(size_t)ff * 4 * W1SZ] = f2bf(tile[kk][fr + ff * 4]);
    } else {
      float* wp = wt2 + ((size_t)b * 64 + fr) * WT2SZ + (k0 - W1SZ) + kk;
#pragma unroll
      for (int ff = 0; ff < 16; ff++)
        wp[(size_t)ff * 4 * WT2SZ] = tile[kk][fr + ff * 4];
    }
  }
}

// ---------------- K1: MFMA conv1, bn1 stats ONLY (no x1 materialization) ----------------
__global__ __launch_bounds__(256) void k1_stats(const float* __restrict__ x,
                                                const unsigned short* __restrict__ wb1,
                                                float* __restrict__ sums) {
  __shared__ __align__(16) unsigned short pL[21 * 512];   // B frags: 21 ij-tiles
  __shared__ float stat[384];
  const int p  = blockIdx.x;
  const int b  = p >> 6;
  const int fi = (p >> 3) & 7;
  const int fj = p & 7;
  const int t  = threadIdx.x;

  for (int i = t; i < 384; i += 256) stat[i] = 0.f;

  // stage patch frags: value B[c][ij] = patch[ij][c] (reflect-pad gather)
  const int row0 = fi * 16 - 1, col0 = fj * 16 - 1;
  const float* xb = x + (size_t)b * 32 * 128 * 128;
  for (int idx = t; idx < 32 * A1; idx += 256) {
    int c  = idx / A1;
    int ij = idx - c * A1;
    int ii = ij / 18;
    int jj = ij - ii * 18;
    int r  = row0 + ii; r  = (r  < 0) ? 1 : (r  > 127) ? 126 : r;
    int cl = col0 + jj; cl = (cl < 0) ? 1 : (cl > 127) ? 126 : cl;
    int slot = ((ij >> 4) * 4 + (c >> 3)) * 128 + (ij & 15) * 8 + (c & 7);
    pL[slot] = f2bf(xb[((size_t)c * 128 + r) * 128 + cl]);
  }
  __syncthreads();

  const int lane = t & 63;
  const int wv   = t >> 6;
  const int m16  = lane & 15;
  const int quad = lane >> 4;
  const unsigned short* wbp = wb1 + (size_t)p * W1SZ;

  for (int oi = 0; oi < 3; oi++) {
    const int ot = wv + oi * 4;                       // 0..11 across 4 waves
    bf16x8 a = *(const bf16x8*)(wbp + ot * 512 + lane * 8);   // pre-swizzled global
    float sacc[4] = {0.f, 0.f, 0.f, 0.f};
    float qacc[4] = {0.f, 0.f, 0.f, 0.f};
    for (int jt = 0; jt < 21; jt++) {
      bf16x8 bb = *(const bf16x8*)&pL[jt * 512 + lane * 8];
      f32x4 d = __builtin_amdgcn_mfma_f32_16x16x32_bf16(a, bb, (f32x4){0.f, 0.f, 0.f, 0.f}, 0, 0, 0);
      const int ij = jt * 16 + m16;                   // D col = lane&15
      if (ij < A1) {
#pragma unroll
        for (int r = 0; r < 4; r++) {                 // D row = quad*4 + r
          float v = d[r];                             // raw fp32 (k2 recomputes same)
          sacc[r] += v;
          qacc[r] = fmaf(v, v, qacc[r]);
        }
      }
    }
#pragma unroll
    for (int r = 0; r < 4; r++) {
      float sv = sacc[r], qv = qacc[r];
#pragma unroll
      for (int msk = 1; msk < 16; msk <<= 1) {
        sv += __shfl_xor(sv, msk, 64);
        qv += __shfl_xor(qv, msk, 64);
      }
      if (m16 == 0) {
        int o = ot * 16 + quad * 4 + r;
        atomicAdd(&stat[o], sv);
        atomicAdd(&stat[192 + o], qv);
      }
    }
  }
  __syncthreads();
  for (int i = t; i < 384; i += 256) atomicAdd(&sums[i], stat[i]);
}

// ---------------- K2: fused conv1-recompute + bn1 + relu6 + depthwise 3x3 + bn2 stats ----
// grid: 512 (one patch per block). x2 layout [p][12 ot][256 ij][16 c] bf16.
// 12 rounds x 1 o-tile; xc layout [c_local][ij pad 328] so dw reads are aligned b32.
__global__ __launch_bounds__(256) void k2_fused(const float* __restrict__ x,
                                                const unsigned short* __restrict__ wb1,
                                                const float* __restrict__ wt2,
                                                const float* __restrict__ sums,
                                                const float* __restrict__ g1,
                                                const float* __restrict__ b1,
                                                unsigned short* __restrict__ x2,
                                                float* __restrict__ sums2) {
  __shared__ __align__(16) unsigned short pL[21 * 512];      // 21504 B
  __shared__ __align__(16) unsigned short xc[16 * 328];      // 10496 B [c][ij pad]
  __shared__ __align__(16) unsigned short x2s[256 * 18];     //  9216 B [ij][16 + 2 pad]
  __shared__ float w2L[HID * 9];                             //  6912 B
  __shared__ float sc[HID], sh[HID];                         //  1536 B
  __shared__ float st2[384];                                 //  1536 B => 51200 B total
  const int p  = blockIdx.x;
  const int b  = p >> 6;
  const int fi = (p >> 3) & 7;
  const int fj = p & 7;
  const int t  = threadIdx.x;

  const float inv1 = 1.f / 165888.f;    // 512*324
  for (int c = t; c < HID; c += 256) {
    float m   = sums[c] * inv1;
    float var = sums[192 + c] * inv1 - m * m;
    float scl = g1[c] * rsqrtf(var + EPS);
    sc[c] = scl;
    sh[c] = b1[c] - m * scl;
  }
  for (int i = t; i < 384; i += 256) st2[i] = 0.f;
  {
    const float* wtp = wt2 + (size_t)p * WT2SZ;   // w2 at offset 0, 1728 floats
    for (int i = t; i < HID * 9; i += 256) w2L[i] = wtp[i];
  }

  // stage patch B-frags (identical to k1)
  const int row0 = fi * 16 - 1, col0 = fj * 16 - 1;
  const float* xb = x + (size_t)b * 32 * 128 * 128;
  for (int idx = t; idx < 32 * A1; idx += 256) {
    int c  = idx / A1;
    int ij = idx - c * A1;
    int ii = ij / 18;
    int jj = ij - ii * 18;
    int r  = row0 + ii; r  = (r  < 0) ? 1 : (r  > 127) ? 126 : r;
    int cl = col0 + jj; cl = (cl < 0) ? 1 : (cl > 127) ? 126 : cl;
    int slot = ((ij >> 4) * 4 + (c >> 3)) * 128 + (ij & 15) * 8 + (c & 7);
    pL[slot] = f2bf(xb[((size_t)c * 128 + r) * 128 + cl]);
  }
  __syncthreads();

  const int lane = t & 63;
  const int wv   = t >> 6;
  const int m16  = lane & 15;
  const int quad = lane >> 4;
  // dw coords: t = ih*128 + cdw*8 + jp
  const int ih  = t >> 7;          // 0..1  (i-half)
  const int cdw = (t >> 3) & 15;   // 0..15 (channel within tile)
  const int jp  = t & 7;           // 0..7  (j-pair)
  const unsigned short* wbp = wb1 + (size_t)p * W1SZ;
  unsigned short* x2base = x2 + (size_t)p * 12 * 4096;

  // ---- conv1 for one o-tile rt -> xc[c][ij] (bn1+relu6 applied) ----
  auto conv1 = [&](int rt) {
    bf16x8 a = *(const bf16x8*)(wbp + rt * 512 + lane * 8);
    for (int jt = wv; jt < 21; jt += 4) {
      bf16x8 bb = *(const bf16x8*)&pL[jt * 512 + lane * 8];
      f32x4 d = __builtin_amdgcn_mfma_f32_16x16x32_bf16(a, bb, (f32x4){0.f, 0.f, 0.f, 0.f}, 0, 0, 0);
      const int ij = jt * 16 + m16;
      if (ij < A1) {
#pragma unroll
        for (int r = 0; r < 4; r++) {
          int cl = quad * 4 + r;
          int ch = rt * 16 + cl;
          float v = relu6f(fmaf(d[r], sc[ch], sh[ch]));
          xc[cl * 328 + ij] = f2bf(v);
        }
      }
    }
  };

  conv1(0);
  __syncthreads();

  for (int rt = 0; rt < 12; rt++) {
    // ---- depthwise on tile rt: thread = (ih, cdw, jp); aligned b32 LDS reads ----
    {
      const int ch = rt * 16 + cdw;
      float wr[9];
#pragma unroll
      for (int u = 0; u < 9; u++) wr[u] = w2L[ch * 9 + u];
      float a0[8], a1[8];
#pragma unroll
      for (int i = 0; i < 8; i++) { a0[i] = 0.f; a1[i] = 0.f; }
      const unsigned short* xcc = &xc[cdw * 328];
#pragma unroll
      for (int rr = 0; rr < 10; rr++) {
        const int rg = ih * 8 + rr;
        unsigned int d0 = *(const unsigned int*)&xcc[rg * 18 + jp * 2];
        unsigned int d1 = *(const unsigned int*)&xcc[rg * 18 + jp * 2 + 2];
        float v0 = bf2f(d0 & 0xFFFFu), v1 = bf2f(d0 >> 16);
        float v2 = bf2f(d1 & 0xFFFFu), v3 = bf2f(d1 >> 16);
#pragma unroll
        for (int u = 0; u < 3; u++) {
          int il = rr - u;
          if (il >= 0 && il < 8) {
            a0[il] = fmaf(v0, wr[u * 3 + 0], fmaf(v1, wr[u * 3 + 1], fmaf(v2, wr[u * 3 + 2], a0[il])));
            a1[il] = fmaf(v1, wr[u * 3 + 0], fmaf(v2, wr[u * 3 + 1], fmaf(v3, wr[u * 3 + 2], a1[il])));
          }
        }
      }
      float ls = 0.f, lq = 0.f;
#pragma unroll
      for (int il = 0; il < 8; il++) {
        const int ig = ih * 8 + il;
        const int j0 = jp * 2;
        unsigned short h0 = f2bf(a0[il]);
        unsigned short h1 = f2bf(a1[il]);
        float r0 = bf2f(h0), r1 = bf2f(h1);
        ls += r0 + r1;
        lq = fmaf(r0, r0, fmaf(r1, r1, lq));
        x2s[(ig * 16 + j0) * 18 + cdw]     = h0;
        x2s[(ig * 16 + j0 + 1) * 18 + cdw] = h1;
      }
      // reduce over jp (lanes cdw*8+jp within wave)
      ls += __shfl_xor(ls, 1, 64); lq += __shfl_xor(lq, 1, 64);
      ls += __shfl_xor(ls, 2, 64); lq += __shfl_xor(lq, 2, 64);
      ls += __shfl_xor(ls, 4, 64); lq += __shfl_xor(lq, 4, 64);
      if (jp == 0) {
        atomicAdd(&st2[ch], ls);
        atomicAdd(&st2[192 + ch], lq);
      }
    }
    __syncthreads();
    // ---- coop store x2s -> global [rt][256][16]; overlap conv1 of next tile ----
    {
      unsigned short* dst = x2base + (size_t)rt * 4096;
#pragma unroll
      for (int k = 0; k < 4; k++) {
        int g  = (k * 256 + t) * 4;          // ushort offset, multiple of 4
        int ij = g >> 4, c0 = g & 15;
        unsigned int v0 = *(const unsigned int*)&x2s[ij * 18 + c0];
        unsigned int v1 = *(const unsigned int*)&x2s[ij * 18 + c0 + 2];
        uint2 v; v.x = v0; v.y = v1;
        *(uint2*)&dst[g] = v;
      }
    }
    if (rt < 11) conv1(rt + 1);
    __syncthreads();
  }
  for (int i = t; i < 384; i += 256) atomicAdd(&sums2[i], st2[i]);
}

// ---------------- K3: MFMA pointwise 192->32, bn2+relu6 fused on B-load ----------------
// grid: 1024 = patch(512) * ij-half(2); x3 bf16 [p][o][256]; bn3 stats (on rounded values)
__global__ __launch_bounds__(256) void k3_pw2(const unsigned short* __restrict__ x2,
                                              const float* __restrict__ wt2,
                                              const float* __restrict__ sums2,
                                              const float* __restrict__ g2,
                                              const float* __restrict__ b2,
                                              unsigned short* __restrict__ x3,
                                              float* __restrict__ sums3) {
  __shared__ __align__(16) unsigned short wA[12 * 512];   // A frags: [ot(2)][ks(6)]
  __shared__ float sc[HID], sh[HID];
  __shared__ float st3[64];
  const int blk  = blockIdx.x;
  const int p    = blk >> 1;
  const int half = blk & 1;
  const int t    = threadIdx.x;
  const float inv = 1.f / 131072.f;   // 512*256
  for (int c = t; c < HID; c += 256) {
    float m   = sums2[c] * inv;
    float var = sums2[192 + c] * inv - m * m;
    float scl = g2[c] * rsqrtf(var + EPS);
    sc[c] = scl;
    sh[c] = b2[c] - m * scl;
  }
  if (t < 64) st3[t] = 0.f;
  // stage w3 -> bf16 A-frags: A[m=o&15][k], frag (ot=o>>4, ks=c>>5)
  const float* w3p = wt2 + (size_t)p * WT2SZ + R3OFF;     // [o][192]
  for (int idx = t; idx < 32 * 48; idx += 256) {
    int o  = idx / 48;
    int c4 = idx - o * 48;
    float4 v = *(const float4*)&w3p[o * HID + c4 * 4];
    int slot = ((o >> 4) * 6 + (c4 >> 3)) * 512 + ((((c4 >> 1) & 3) * 16) + (o & 15)) * 8 + (c4 & 1) * 4;
    ushort4 u;
    u.x = f2bf(v.x); u.y = f2bf(v.y); u.z = f2bf(v.z); u.w = f2bf(v.w);
    *(ushort4*)&wA[slot] = u;
  }
  __syncthreads();
  const int lane = t & 63;
  const int wv   = t >> 6;
  const int m16  = lane & 15;
  const int kg   = lane >> 4;
  bf16x8 aF[2][6];
#pragma unroll
  for (int ot = 0; ot < 2; ot++)
#pragma unroll
    for (int ks = 0; ks < 6; ks++)
      aF[ot][ks] = *(const bf16x8*)&wA[(ot * 6 + ks) * 512 + lane * 8];
  const unsigned short* x2p = x2 + (size_t)p * 12 * 4096;
  f32x4 acc[2][2];
#pragma unroll
  for (int it = 0; it < 2; it++)
#pragma unroll
    for (int ot = 0; ot < 2; ot++)
#pragma unroll
      for (int r = 0; r < 4; r++) acc[it][ot][r] = 0.f;
#pragma unroll
  for (int it = 0; it < 2; it++) {
    const int ijt = half * 8 + wv + it * 4;
    const int ij  = ijt * 16 + m16;
    // x2 [ot12][ij][16]: for k = ks*32 + kg*8 + j, addr = ks*8192 + (kg>>1)*4096 + ij*16 + (kg&1)*8
    const unsigned short* brow = x2p + (size_t)(kg >> 1) * 4096 + (size_t)ij * 16 + (kg & 1) * 8;
#pragma unroll
    for (int ks = 0; ks < 6; ks++) {
      ushort4 u0 = *(const ushort4*)&brow[ks * 8192];
      ushort4 u1 = *(const ushort4*)&brow[ks * 8192 + 4];
      const float* scp = &sc[ks * 32 + kg * 8];
      const float* shp = &sh[ks * 32 + kg * 8];
      unsigned short uu[8] = {u0.x, u0.y, u0.z, u0.w, u1.x, u1.y, u1.z, u1.w};
      bf16x8 bb;
#pragma unroll
      for (int j = 0; j < 8; j++) {
        float y = relu6f(fmaf(bf2f(uu[j]), scp[j], shp[j]));
        bb[j] = (short)f2bf(y);
      }
      acc[it][0] = __builtin_amdgcn_mfma_f32_16x16x32_bf16(aF[0][ks], bb, acc[it][0], 0, 0, 0);
      acc[it][1] = __builtin_amdgcn_mfma_f32_16x16x32_bf16(aF[1][ks], bb, acc[it][1], 0, 0, 0);
    }
  }
  unsigned short* x3p = x3 + (size_t)p * 32 * A2;
  float sacc[2][4] = {{0.f}}, qacc[2][4] = {{0.f}};
#pragma unroll
  for (int it = 0; it < 2; it++) {
    const int ijt = half * 8 + wv + it * 4;
#pragma unroll
    for (int ot = 0; ot < 2; ot++) {
#pragma unroll
      for (int r = 0; r < 4; r++) {
        unsigned short h = f2bf(acc[it][ot][r]);
        float v = bf2f(h);
        x3p[(size_t)(ot * 16 + kg * 4 + r) * A2 + ijt * 16 + m16] = h;
        sacc[ot][r] += v;
        qacc[ot][r] = fmaf(v, v, qacc[ot][r]);
      }
    }
  }
#pragma unroll
  for (int ot = 0; ot < 2; ot++)
#pragma unroll
    for (int r = 0; r < 4; r++) {
      float sv = sacc[ot][r], qv = qacc[ot][r];
#pragma unroll
      for (int msk = 1; msk < 16; msk <<= 1) {
        sv += __shfl_xor(sv, msk, 64);
        qv += __shfl_xor(qv, msk, 64);
      }
      if (m16 == 0) {
        int o = ot * 16 + kg * 4 + r;
        atomicAdd(&st3[o], sv);
        atomicAdd(&st3[32 + o], qv);
      }
    }
  __syncthreads();
  if (t < 64) atomicAdd(&sums3[t], st3[t]);
}

// ---------------- K4: bn3 + residual + layout transform ----------------
__global__ __launch_bounds__(256) void k4_out(const float* __restrict__ x,
                                              const unsigned short* __restrict__ x3,
                                              const float* __restrict__ sums3,
                                              const float* __restrict__ g3,
                                              const float* __restrict__ b3,
                                              float* __restrict__ out) {
  const int idx4 = blockIdx.x * 256 + threadIdx.x;   // 1,048,576 float4 total
  const int w4 = idx4 & 31;
  int tmp = idx4 >> 5;
  const int h = tmp & 127; tmp >>= 7;
  const int o = tmp & 31;
  const int b = tmp >> 5;
  const int fi = h >> 4, i = h & 15;
  const int fj = w4 >> 2;
  const int j0 = (w4 & 3) * 4;
  const int p   = b * 64 + fi * 8 + fj;
  const int ij0 = i * 16 + j0;
  const float inv = 1.f / 131072.f;
  float m   = sums3[o] * inv;
  float var = sums3[32 + o] * inv - m * m;
  float sv  = g3[o] * rsqrtf(var + EPS);
  float shv = b3[o] - m * sv;
  float4 xv = *(const float4*)&x[(size_t)idx4 * 4];
  ushort4 u = *(const ushort4*)&x3[((size_t)p * 32 + o) * A2 + ij0];
  float4 r;
  r.x = fmaf(bf2f(u.x), sv, shv) + xv.x;
  r.y = fmaf(bf2f(u.y), sv, shv) + xv.y;
  r.z = fmaf(bf2f(u.z), sv, shv) + xv.z;
  r.w = fmaf(bf2f(u.w), sv, shv) + xv.w;
  *(float4*)&out[(size_t)idx4 * 4] = r;
}

extern "C" void kernel_launch(void* const* d_in, const int* in_sizes, int n_in,
                              void* d_out, int out_size, void* d_ws, size_t ws_size,
                              hipStream_t stream) {
  const float* x  = (const float*)d_in[0];
  const float* s  = (const float*)d_in[1];
  const float* g1 = (const float*)d_in[2];
  const float* b1 = (const float*)d_in[3];
  const float* g2 = (const float*)d_in[4];
  const float* b2 = (const float*)d_in[5];
  const float* g3 = (const float*)d_in[6];
  const float* b3 = (const float*)d_in[7];
  char* base = (char*)d_ws;
  unsigned short* wb1  = (unsigned short*)(base + WB1_B);
  float*          wt2  = (float*)(base + WT2_B);
  unsigned short* x2   = (unsigned short*)(base + X2_B);
  unsigned short* x3   = (unsigned short*)(base + X3_B);
  float*          sums = (float*)(base + SUM_B);
  float* out = (float*)d_out;

  hipMemsetAsync(sums, 0, 832 * sizeof(float), stream);
  k0_transpose<<<8 * 219, 256, 0, stream>>>(s, wb1, wt2);
  k1_stats<<<P_TOT, 256, 0, stream>>>(x, wb1, sums);
  k2_fused<<<P_TOT, 256, 0, stream>>>(x, wb1, wt2, sums, g1, b1, x2, sums + 384);
  k3_pw2<<<1024, 256, 0, stream>>>(x2, wt2, sums + 384, g2, b2, x3, sums + 768);
  k4_out<<<4096, 256, 0, stream>>>(x, x3, sums + 768, g3, b3, out);
}